// Round 4
// baseline (1067.926 us; speedup 1.0000x reference)
//
#include <hip/hip_runtime.h>
#include <math.h>

namespace {

typedef unsigned short bf16_t;
typedef __bf16  bf16x8_t __attribute__((ext_vector_type(8)));
typedef float   f32x4_t  __attribute__((ext_vector_type(4)));
typedef unsigned int u32x4 __attribute__((ext_vector_type(4)));

constexpr int G     = 4096;      // BS*E
constexpr int GA    = 32768;     // G*A
constexpr int WDIM  = 300;
constexpr int KPAD  = 320;
constexpr int HDIM  = 1024;
constexpr int NNODE = 9;
constexpr int MROWS = G * NNODE; // 36864
constexpr int TE_   = 8;
constexpr int TA_   = 4;
constexpr int V_    = 30522;
constexpr int VP    = 30592;     // 239*128
constexpr int PROJW = 1024;

__device__ __forceinline__ float bf2f(bf16_t b) {
    union { unsigned int u; float f; } v; v.u = ((unsigned int)b) << 16; return v.f;
}
__device__ __forceinline__ bf16_t f2bf(float f) {
    union { float f; unsigned int u; } v; v.f = f;
    unsigned int r = v.u + 0x7FFFu + ((v.u >> 16) & 1u);   // RNE
    return (bf16_t)(r >> 16);
}

// =====================================================================
// Generic 128x128-tile bf16 MFMA GEMM (validated R3/R4): C = A[M,K] @ B[N,K]^T
// MODE 0: C bf16 (vocab projection)   MODE 2: C fp32 with elu (final out)
// =====================================================================
template<int MODE>
__global__ __launch_bounds__(256)
void mfma_gemm(const bf16_t* __restrict__ A, const bf16_t* __restrict__ B,
               void* __restrict__ Cv, int lda, int ldb, int ldc, int K)
{
    __shared__ bf16_t As[128 * 32];
    __shared__ bf16_t Bs[128 * 32];

    const int tid  = threadIdx.x;
    const int w    = tid >> 6;
    const int lane = tid & 63;
    const int wr = w >> 1, wc = w & 1;
    const int lr = lane & 15;
    const int lk = lane >> 4;
    const int m0 = blockIdx.x * 128, n0 = blockIdx.y * 128;

    const int r0 = tid >> 2;
    const int cc = (tid & 3) * 8;
    const bf16_t* Arow0 = A + (size_t)(m0 + r0) * lda + cc;
    const bf16_t* Arow1 = Arow0 + (size_t)64 * lda;
    const bf16_t* Brow0 = B + (size_t)(n0 + r0) * ldb + cc;
    const bf16_t* Brow1 = Brow0 + (size_t)64 * ldb;

    f32x4_t acc[4][4];
#pragma unroll
    for (int i = 0; i < 4; ++i)
#pragma unroll
        for (int j = 0; j < 4; ++j) acc[i][j] = {0.f, 0.f, 0.f, 0.f};

    for (int k0 = 0; k0 < K; k0 += 32) {
        const uint4 a0 = *(const uint4*)(Arow0 + k0);
        const uint4 a1 = *(const uint4*)(Arow1 + k0);
        const uint4 b0 = *(const uint4*)(Brow0 + k0);
        const uint4 b1 = *(const uint4*)(Brow1 + k0);
        __syncthreads();
        *(uint4*)&As[r0 * 32 + cc]        = a0;
        *(uint4*)&As[(r0 + 64) * 32 + cc] = a1;
        *(uint4*)&Bs[r0 * 32 + cc]        = b0;
        *(uint4*)&Bs[(r0 + 64) * 32 + cc] = b1;
        __syncthreads();

        bf16x8_t af[4], bfr[4];
#pragma unroll
        for (int i = 0; i < 4; ++i) {
            af[i]  = *(const bf16x8_t*)&As[(wr * 64 + i * 16 + lr) * 32 + lk * 8];
            bfr[i] = *(const bf16x8_t*)&Bs[(wc * 64 + i * 16 + lr) * 32 + lk * 8];
        }
#pragma unroll
        for (int mi = 0; mi < 4; ++mi)
#pragma unroll
            for (int ni = 0; ni < 4; ++ni)
                acc[mi][ni] = __builtin_amdgcn_mfma_f32_16x16x32_bf16(
                    af[mi], bfr[ni], acc[mi][ni], 0, 0, 0);
    }

#pragma unroll
    for (int mi = 0; mi < 4; ++mi) {
#pragma unroll
        for (int ni = 0; ni < 4; ++ni) {
            const int n = n0 + wc * 64 + ni * 16 + lr;
#pragma unroll
            for (int r = 0; r < 4; ++r) {
                const int m = m0 + wr * 64 + mi * 16 + lk * 4 + r;
                const float v = acc[mi][ni][r];
                if (MODE == 0)
                    ((bf16_t*)Cv)[(size_t)m * ldc + n] = f2bf(v);
                else
                    ((float*)Cv)[(size_t)m * ldc + n] = v > 0.f ? v : expm1f(v);
            }
        }
    }
}

// =====================================================================
// Attr GRU step (R14): fused GEMM + gate epilogue with A-tile reuse.
// Replaces R6 gru_attr_step (112 us/step: scalar 2B xp gathers + 100
// barriers/step were latency-bound at MfmaUtil 7%).
// Block = 64 rows; h staged ONCE in LDS (41 KB); loops the 8 N-slices
// (120 interleaved gate cols each, n = 3j+g) internally: per slice a
// 64x120 MFMA tile (K=320), scatter to gsm (col<120 guard — R12 lesson),
// then the fused epilogue reads xp as 15 contiguous dwords/thread from
// the interleaved proj. 2 blocks/CU (81.2 KB LDS). No early return in
// the nb loop (barrier uniformity) — epilogue is predicated instead.
// =====================================================================
__global__ __launch_bounds__(256)
void gru_attr_fused(const bf16_t* __restrict__ hin,     // [GA][KPAD]
                    bf16_t* __restrict__ hout,          // [GA][KPAD]
                    const bf16_t* __restrict__ Whh3i,   // [1024][320] n=3j+g
                    const bf16_t* __restrict__ proj,    // [VP][1024]  n=3j+g
                    const int* __restrict__ tokens,
                    const int* __restrict__ lengths,
                    const float* __restrict__ bih, const float* __restrict__ bhh,
                    int T, int t)
{
    constexpr int ASTR  = 328;               // bf16 row stride (bank offset 4/row)
    constexpr int GSTRF = 121;               // f32 stride; 120 used cols
    __shared__ __align__(16) bf16_t As[64 * ASTR];   // 41984 B
    __shared__ __align__(16) bf16_t Bs[128 * 32];    //  8192 B
    __shared__ float gsm[64 * GSTRF];                // 30976 B

    const int tid = threadIdx.x;
    const int w = tid >> 6, lane = tid & 63;
    const int lr = lane & 15, lk = lane >> 4;
    const int m0 = blockIdx.x * 64;

    // stage h tile once: 64 rows x 320 cols (2560 x 16B)
#pragma unroll
    for (int it = 0; it < 10; ++it) {
        const int i = tid + 256 * it;
        const int row = i / 40, c8 = (i - row * 40) * 8;
        const uint4 v = *(const uint4*)(hin + (size_t)(m0 + row) * KPAD + c8);
        *(uint4*)&As[row * ASTR + c8] = v;
    }
    __syncthreads();

    // epilogue thread mapping: thread -> (row ml, quarter q)
    const int ml = tid >> 2, q = tid & 3;
    const int m  = m0 + ml;
    int len = lengths[m]; if (len < 1) len = 1;
    const bool act = (t < len);
    const int tok = tokens[(size_t)m * T + t];

    for (int nb = 0; nb < 8; ++nb) {
        const int n0 = nb * 120;

        f32x4_t acc[4][2];
#pragma unroll
        for (int mi = 0; mi < 4; ++mi)
#pragma unroll
            for (int ni = 0; ni < 2; ++ni) acc[mi][ni] = {0.f, 0.f, 0.f, 0.f};

        for (int k0 = 0; k0 < KPAD; k0 += 32) {
            // stage Bs: 128 rows x 32 K = 512 x 16B, 2 per thread
            uint4 bv[2];
#pragma unroll
            for (int p = 0; p < 2; ++p) {
                const int i = tid + 256 * p;
                const int rr_ = i >> 2, c8 = (i & 3) * 8;
                bv[p] = *(const uint4*)(Whh3i + (size_t)(n0 + rr_) * KPAD + k0 + c8);
            }
            __syncthreads();   // prior Bs reads (and prior-nb gsm reads) done
#pragma unroll
            for (int p = 0; p < 2; ++p) {
                const int i = tid + 256 * p;
                const int rr_ = i >> 2, c8 = (i & 3) * 8;
                *(uint4*)&Bs[rr_ * 32 + c8] = bv[p];
            }
            __syncthreads();

            bf16x8_t af[4], bfr[2];
#pragma unroll
            for (int mi = 0; mi < 4; ++mi)
                af[mi] = *(const bf16x8_t*)&As[(mi * 16 + lr) * ASTR + k0 + lk * 8];
#pragma unroll
            for (int ni = 0; ni < 2; ++ni)
                bfr[ni] = *(const bf16x8_t*)&Bs[(w * 32 + ni * 16 + lr) * 32 + lk * 8];
#pragma unroll
            for (int mi = 0; mi < 4; ++mi)
#pragma unroll
                for (int ni = 0; ni < 2; ++ni)
                    acc[mi][ni] = __builtin_amdgcn_mfma_f32_16x16x32_bf16(
                        af[mi], bfr[ni], acc[mi][ni], 0, 0, 0);
        }

        // scatter to gsm; cols >= 120 are B-stage overlap — do not scatter
#pragma unroll
        for (int ni = 0; ni < 2; ++ni) {
            const int col = w * 32 + ni * 16 + lr;
            if (col < 120) {
#pragma unroll
                for (int mi = 0; mi < 4; ++mi)
#pragma unroll
                    for (int r = 0; r < 4; ++r)
                        gsm[(mi * 16 + lk * 4 + r) * GSTRF + col] = acc[mi][ni][r];
            }
        }
        __syncthreads();

        // fused epilogue for j-range [nb*40 + q*10, +10); predicated, no return
        if (!(nb == 7 && q >= 2)) {
            const int jb = nb * 40 + q * 10;
            const unsigned int* xpp =
                (const unsigned int*)(proj + (size_t)tok * PROJW + n0 + q * 30);
            unsigned int xw[15];
#pragma unroll
            for (int i = 0; i < 15; ++i) xw[i] = xpp[i];

            unsigned int ow[5];
#pragma unroll
            for (int u = 0; u < 10; ++u) {
                const int j = jb + u;
                const float hold = bf2f(As[ml * ASTR + j]);
                float hv = hold;
                if (act) {
                    const int e0 = 3 * u;
                    const float xr = bf2f((bf16_t)((e0 & 1)       ? (xw[e0 >> 1] >> 16)       : (xw[e0 >> 1] & 0xffff)));
                    const float xz = bf2f((bf16_t)(((e0 + 1) & 1) ? (xw[(e0 + 1) >> 1] >> 16) : (xw[(e0 + 1) >> 1] & 0xffff)));
                    const float xn = bf2f((bf16_t)(((e0 + 2) & 1) ? (xw[(e0 + 2) >> 1] >> 16) : (xw[(e0 + 2) >> 1] & 0xffff)));
                    const int nl = q * 30 + 3 * u;
                    const float g0 = gsm[ml * GSTRF + nl];
                    const float g1 = gsm[ml * GSTRF + nl + 1];
                    const float g2 = gsm[ml * GSTRF + nl + 2];
                    const float rr = 1.f / (1.f + expf(-(g0 + xr + bih[j] + bhh[j])));
                    const float zz = 1.f / (1.f + expf(-(g1 + xz + bih[WDIM + j] + bhh[WDIM + j])));
                    const float nn = tanhf(xn + bih[2 * WDIM + j] + rr * (g2 + bhh[2 * WDIM + j]));
                    hv = (1.f - zz) * nn + zz * hold;
                }
                const bf16_t hb_ = f2bf(hv);
                if ((u & 1) == 0) ow[u >> 1] = hb_;
                else              ow[u >> 1] |= ((unsigned int)hb_) << 16;
            }
            unsigned int* outp = (unsigned int*)(hout + (size_t)m * KPAD + jb);
#pragma unroll
            for (int i = 0; i < 5; ++i) outp[i] = ow[i];
        }
        // next nb's first __syncthreads (inside k-loop) separates gsm reuse
    }
}

// =====================================================================
// Ent GRU step (R13-validated): one launch per step; fused GEMM + gate
// epilogue. gates[4096x960] = h @ Whh3i^T, tile M=128 x N=120, grid 32x8,
// 512 thr. Scatter guarded col<120 (R12 race lesson).
// =====================================================================
__global__ __launch_bounds__(512)
void gru_step_fused(const bf16_t* __restrict__ hin,     // [G][KPAD]
                    bf16_t* __restrict__ hout,          // [G][KPAD]
                    const bf16_t* __restrict__ Whh3i,   // [1024][320] n=3j+g
                    const bf16_t* __restrict__ proj,    // [VP][1024]  n=3j+g
                    const int* __restrict__ tokens,
                    const int* __restrict__ lengths,
                    const float* __restrict__ bih, const float* __restrict__ bhh,
                    int T, int t)
{
    constexpr int GSTRF = 123;               // odd f32 stride; 120 used cols
    __shared__ __align__(16) bf16_t As[128 * 32];   // 8 KB
    __shared__ __align__(16) bf16_t Bs[128 * 32];   // 8 KB
    __shared__ float gsm[128 * GSTRF];              // 61.5 KB

    const int tid = threadIdx.x;
    const int w = tid >> 6, lane = tid & 63;
    const int lr = lane & 15, lk = lane >> 4;
    const int wr = w >> 2, wc = w & 3;       // 2 (M) x 4 (N) waves
    const int m0 = blockIdx.x * 128;
    const int nb = blockIdx.y;               // 0..7
    const int n0 = nb * 120;

    const int sr = tid >> 2, sc = (tid & 3) * 8;
    const bf16_t* Ap = hin   + (size_t)(m0 + sr) * KPAD + sc;
    const bf16_t* Bp = Whh3i + (size_t)(n0 + sr) * KPAD + sc;

    f32x4_t acc[4][2];
#pragma unroll
    for (int mi = 0; mi < 4; ++mi)
#pragma unroll
        for (int ni = 0; ni < 2; ++ni) acc[mi][ni] = {0.f, 0.f, 0.f, 0.f};

    for (int k0 = 0; k0 < KPAD; k0 += 32) {
        const uint4 av = *(const uint4*)(Ap + k0);
        const uint4 bv = *(const uint4*)(Bp + k0);
        __syncthreads();
        *(uint4*)&As[sr * 32 + sc] = av;
        *(uint4*)&Bs[sr * 32 + sc] = bv;
        __syncthreads();

        bf16x8_t af[4], bfr[2];
#pragma unroll
        for (int mi = 0; mi < 4; ++mi)
            af[mi] = *(const bf16x8_t*)&As[(wr * 64 + mi * 16 + lr) * 32 + lk * 8];
#pragma unroll
        for (int ni = 0; ni < 2; ++ni)
            bfr[ni] = *(const bf16x8_t*)&Bs[(wc * 32 + ni * 16 + lr) * 32 + lk * 8];
#pragma unroll
        for (int mi = 0; mi < 4; ++mi)
#pragma unroll
            for (int ni = 0; ni < 2; ++ni)
                acc[mi][ni] = __builtin_amdgcn_mfma_f32_16x16x32_bf16(
                    af[mi], bfr[ni], acc[mi][ni], 0, 0, 0);
    }

    // scatter wave tiles to gates LDS (row = M, col = N); cols >= 120 are
    // the B-stage overlap belonging to the next nb block — DO NOT scatter
#pragma unroll
    for (int ni = 0; ni < 2; ++ni) {
        const int col = wc * 32 + ni * 16 + lr;
        if (col < 120) {
#pragma unroll
            for (int mi = 0; mi < 4; ++mi)
#pragma unroll
                for (int r = 0; r < 4; ++r)
                    gsm[(wr * 64 + mi * 16 + lk * 4 + r) * GSTRF + col]
                        = acc[mi][ni][r];
        }
    }
    __syncthreads();

    // ---- fused GRU epilogue: thread -> (row ml, quarter q), 10 j each ----
    const int ml = tid >> 2, q = tid & 3;
    if (nb == 7 && q >= 2) return;           // j >= 300 (boundary is exact)
    const int m  = m0 + ml;
    const int jb = nb * 40 + q * 10;
    int len = lengths[m]; if (len < 1) len = 1;
    const bool act = (t < len);
    const int tok = tokens[(size_t)m * T + t];

    const unsigned int* xpp =
        (const unsigned int*)(proj + (size_t)tok * PROJW + n0 + q * 30);
    unsigned int xw[15];
#pragma unroll
    for (int i = 0; i < 15; ++i) xw[i] = xpp[i];

    const unsigned int* hop = (const unsigned int*)(hin + (size_t)m * KPAD + jb);
    unsigned int hw[5];
#pragma unroll
    for (int i = 0; i < 5; ++i) hw[i] = hop[i];

    unsigned int ow[5];
#pragma unroll
    for (int u = 0; u < 10; ++u) {
        const int j = jb + u;
        const bf16_t hob = (bf16_t)((u & 1) ? (hw[u >> 1] >> 16) : (hw[u >> 1] & 0xffff));
        const float hold = bf2f(hob);
        float hv = hold;
        if (act) {
            const int e0 = 3 * u;
            const float xr = bf2f((bf16_t)((e0 & 1)       ? (xw[e0 >> 1] >> 16)       : (xw[e0 >> 1] & 0xffff)));
            const float xz = bf2f((bf16_t)(((e0 + 1) & 1) ? (xw[(e0 + 1) >> 1] >> 16) : (xw[(e0 + 1) >> 1] & 0xffff)));
            const float xn = bf2f((bf16_t)(((e0 + 2) & 1) ? (xw[(e0 + 2) >> 1] >> 16) : (xw[(e0 + 2) >> 1] & 0xffff)));
            const int nl = q * 30 + 3 * u;
            const float g0 = gsm[ml * GSTRF + nl];
            const float g1 = gsm[ml * GSTRF + nl + 1];
            const float g2 = gsm[ml * GSTRF + nl + 2];
            const float rr = 1.f / (1.f + expf(-(g0 + xr + bih[j] + bhh[j])));
            const float zz = 1.f / (1.f + expf(-(g1 + xz + bih[WDIM + j] + bhh[WDIM + j])));
            const float nn = tanhf(xn + bih[2 * WDIM + j] + rr * (g2 + bhh[2 * WDIM + j]));
            hv = (1.f - zz) * nn + zz * hold;
        }
        const bf16_t hb_ = f2bf(hv);
        if ((u & 1) == 0) ow[u >> 1] = hb_;
        else              ow[u >> 1] |= ((unsigned int)hb_) << 16;
    }
    unsigned int* outp = (unsigned int*)(hout + (size_t)m * KPAD + jb);
#pragma unroll
    for (int i = 0; i < 5; ++i) outp[i] = ow[i];
}

// =====================================================================
// FC + relu -> nodes (bf16) with FUSED es/ed (R6-validated).
// =====================================================================
__global__ __launch_bounds__(256)
void fc_nodes_esed(const bf16_t* __restrict__ hEnt, const bf16_t* __restrict__ hAtt,
                   const bf16_t* __restrict__ WfcB, const float* __restrict__ bfc,
                   const float* __restrict__ asW, const float* __restrict__ adW,
                   bf16_t* __restrict__ nodes, float* __restrict__ es, float* __restrict__ ed)
{
    constexpr int ASTR = 328;
    __shared__ bf16_t As[64 * ASTR];          // 41 KB
    __shared__ bf16_t Bs[64 * 32];            // 4 KB
    __shared__ const bf16_t* rowp[64];

    const int tid = threadIdx.x;
    const int w = tid >> 6, lane = tid & 63;
    const int lr = lane & 15, lk = lane >> 4;
    const int m0 = blockIdx.x * 64;

    if (tid < 64) {
        const int m = m0 + tid;
        const int g = m / NNODE, i = m - g * NNODE;
        rowp[tid] = (i == 0) ? (hEnt + (size_t)g * KPAD)
                             : (hAtt + (size_t)(g * 8 + (i - 1)) * KPAD);
    }
    __syncthreads();

#pragma unroll
    for (int it = 0; it < 10; ++it) {
        const int i = tid + 256 * it;
        const int row = i / 40, c8 = (i - row * 40) * 8;
        const uint4 v = *(const uint4*)(rowp[row] + c8);
        *(uint4*)&As[row * ASTR + c8] = v;
    }
    __syncthreads();

    float esa[4] = {0.f, 0.f, 0.f, 0.f};
    float eda[4] = {0.f, 0.f, 0.f, 0.f};

    for (int nt = 0; nt < 16; ++nt) {
        const int n0 = nt * 64;
        f32x4_t acc[4];
#pragma unroll
        for (int ni = 0; ni < 4; ++ni) acc[ni] = {0.f, 0.f, 0.f, 0.f};

        for (int k0 = 0; k0 < KPAD; k0 += 32) {
            const int rr_ = tid >> 2, c8 = (tid & 3) * 8;
            const uint4 bv = *(const uint4*)(WfcB + (size_t)(n0 + rr_) * KPAD + k0 + c8);
            __syncthreads();
            *(uint4*)&Bs[rr_ * 32 + c8] = bv;
            __syncthreads();

            const bf16x8_t af = *(const bf16x8_t*)&As[(w * 16 + lr) * ASTR + k0 + lk * 8];
#pragma unroll
            for (int ni = 0; ni < 4; ++ni) {
                const bf16x8_t bfr = *(const bf16x8_t*)&Bs[(ni * 16 + lr) * 32 + lk * 8];
                acc[ni] = __builtin_amdgcn_mfma_f32_16x16x32_bf16(af, bfr, acc[ni], 0, 0, 0);
            }
        }

#pragma unroll
        for (int ni = 0; ni < 4; ++ni) {
            const int n = n0 + ni * 16 + lr;
            const float aw = asW[n], dw = adW[n], bb = bfc[n];
#pragma unroll
            for (int r = 0; r < 4; ++r) {
                float v = acc[ni][r] + bb;
                v = v > 0.f ? v : 0.f;
                const int m = m0 + w * 16 + lk * 4 + r;
                nodes[(size_t)m * HDIM + n] = f2bf(v);
                esa[r] = fmaf(v, aw, esa[r]);
                eda[r] = fmaf(v, dw, eda[r]);
            }
        }
    }

    // reduce across the 16 lr lanes
#pragma unroll
    for (int r = 0; r < 4; ++r) {
        float s = esa[r], d = eda[r];
#pragma unroll
        for (int mask = 1; mask < 16; mask <<= 1) {
            s += __shfl_xor(s, mask, 64);
            d += __shfl_xor(d, mask, 64);
        }
        if (lr == 0) {
            const int m = m0 + w * 16 + lk * 4 + r;
            es[m] = s; ed[m] = d;
        }
    }
}

// =====================================================================
// Prep kernels
// =====================================================================
__global__ __launch_bounds__(256)
void convert_emb_kernel(const float* __restrict__ emb, bf16_t* __restrict__ embB)
{
    const int idx = blockIdx.x * 256 + threadIdx.x;    // over V_*40
    if (idx >= V_ * 40) return;
    const int row = idx / 40, c8 = (idx - row * 40) * 8;
    bf16_t o[8];
#pragma unroll
    for (int e = 0; e < 8; ++e) {
        const int c = c8 + e;
        o[e] = (c < WDIM) ? f2bf(emb[(size_t)row * WDIM + c]) : (bf16_t)0;
    }
    *(ushort4*)(embB + (size_t)row * KPAD + c8)     = *(ushort4*)&o[0];
    *(ushort4*)(embB + (size_t)row * KPAD + c8 + 4) = *(ushort4*)&o[4];
}

// W [3*300][300] fp32 -> dst[1024][320] bf16, INTERLEAVED rows n = 3*j + g
__global__ __launch_bounds__(256)
void build_w3i_kernel(const float* __restrict__ W, bf16_t* __restrict__ dst)
{
    const int idx = blockIdx.x * 256 + threadIdx.x;    // over 1024*320
    if (idx >= HDIM * KPAD) return;
    const int n = idx / KPAD, k = idx - n * KPAD;
    float v = 0.f;
    if (n < 960) {
        const int j = n / 3, g = n - j * 3;
        if (j < WDIM && k < WDIM)
            v = W[(size_t)(g * WDIM + j) * WDIM + k];
    }
    dst[idx] = f2bf(v);
}

__global__ __launch_bounds__(256)
void build_wfc_kernel(const float* __restrict__ Wfc, bf16_t* __restrict__ Wb)
{
    const int idx = blockIdx.x * 256 + threadIdx.x;    // over 1024*320
    if (idx >= HDIM * KPAD) return;
    const int n = idx / KPAD, k = idx - n * KPAD;
    Wb[idx] = f2bf(k < WDIM ? Wfc[(size_t)n * WDIM + k] : 0.f);
}

__global__ __launch_bounds__(256)
void build_wg_kernel(const float* __restrict__ Wg, bf16_t* __restrict__ Wb)
{
    const int idx = blockIdx.x * 256 + threadIdx.x;    // over 1024*1024
    Wb[idx] = f2bf(Wg[idx]);
}

// asW = a_src @ Wg, adW = a_dst @ Wg
__global__ __launch_bounds__(256)
void asw_kernel(const float* __restrict__ Wg,
                const float* __restrict__ a_src, const float* __restrict__ a_dst,
                float* __restrict__ asW, float* __restrict__ adW)
{
    const int k = blockIdx.x * 256 + threadIdx.x;
    float s = 0.f, d = 0.f;
    for (int n = 0; n < HDIM; ++n) {
        const float w = Wg[(size_t)n * HDIM + k];
        s = fmaf(a_src[n], w, s);
        d = fmaf(a_dst[n], w, d);
    }
    asW[k] = s; adW[k] = d;
}

// Row-0 star attention -> mixed[g] = sum_j alpha_j * nodes[g*9+j] (bf16)
__global__ __launch_bounds__(256)
void attn_mix_kernel(const bf16_t* __restrict__ nodes,
                     const float* __restrict__ es, const float* __restrict__ ed,
                     bf16_t* __restrict__ mixed)
{
    const int g = blockIdx.x;
    const float e0 = es[(size_t)g * NNODE];
    const float* edg = ed + (size_t)g * NNODE;

    float w[NNODE], mx = -1e30f;
#pragma unroll
    for (int j = 0; j < NNODE; ++j) {
        float v = e0 + edg[j];
        v = v >= 0.f ? v : 0.2f * v;
        w[j] = v; mx = fmaxf(mx, v);
    }
    float denom = 0.f;
#pragma unroll
    for (int j = 0; j < NNODE; ++j) { w[j] = expf(w[j] - mx); denom += w[j]; }
    const float inv = 1.f / denom;

    const int c = threadIdx.x * 4;
    float4 acc = {0.f, 0.f, 0.f, 0.f};
#pragma unroll
    for (int j = 0; j < NNODE; ++j) {
        const float a = w[j] * inv;
        const ushort4 h4 = *(const ushort4*)(nodes + (size_t)(g * NNODE + j) * HDIM + c);
        acc.x = fmaf(a, bf2f(h4.x), acc.x);
        acc.y = fmaf(a, bf2f(h4.y), acc.y);
        acc.z = fmaf(a, bf2f(h4.z), acc.z);
        acc.w = fmaf(a, bf2f(h4.w), acc.w);
    }
    ushort4 o;
    o.x = f2bf(acc.x); o.y = f2bf(acc.y); o.z = f2bf(acc.z); o.w = f2bf(acc.w);
    *(ushort4*)(mixed + (size_t)g * HDIM + c) = o;
}

// -------- workspace layout (~134 MiB; 157 MiB known-safe) --------
constexpr size_t SZ_EMBB  = (size_t)VP * KPAD * sizeof(bf16_t);      // 19.58 MB
constexpr size_t SZ_PROJ  = (size_t)VP * PROJW * sizeof(bf16_t);     // 62.65 MB
constexpr size_t SZ_HATT  = (size_t)GA * KPAD * sizeof(bf16_t);      // 20.97 MB x2
constexpr size_t SZ_HENT  = (size_t)G * KPAD * sizeof(bf16_t);       //  2.62 MB x2
constexpr size_t SZ_WIH3  = (size_t)HDIM * KPAD * sizeof(bf16_t);
constexpr size_t SZ_WHH3E = (size_t)HDIM * KPAD * sizeof(bf16_t);    //  0.66 MB x2 (1024 rows)
constexpr size_t SZ_WFC   = (size_t)HDIM * KPAD * sizeof(bf16_t);
constexpr size_t SZ_WG    = (size_t)HDIM * HDIM * sizeof(bf16_t);
constexpr size_t SZ_AW    = (size_t)HDIM * sizeof(float);
constexpr size_t SZ_VEC   = (size_t)MROWS * sizeof(float);
constexpr size_t SZ_NODE  = (size_t)MROWS * HDIM * sizeof(bf16_t);   // 75.5 MB
constexpr size_t SZ_MIX   = (size_t)G * HDIM * sizeof(bf16_t);
constexpr size_t WS_NEED  = SZ_EMBB + SZ_PROJ + 2 * SZ_HATT + 2 * SZ_HENT +
                            SZ_WIH3 + 2 * SZ_WHH3E + SZ_WFC + SZ_WG +
                            2 * SZ_AW + 2 * SZ_VEC;
static_assert(SZ_NODE <= SZ_EMBB + SZ_PROJ, "nodes overlays embB+proj");
static_assert(SZ_MIX  <= 2 * SZ_HATT,       "mixed overlays hAtt pair");

} // namespace

extern "C" void kernel_launch(void* const* d_in, const int* in_sizes, int n_in,
                              void* d_out, int out_size, void* d_ws, size_t ws_size,
                              hipStream_t stream)
{
    (void)in_sizes; (void)n_in; (void)out_size;
    if (ws_size < WS_NEED) return;   // clean absmax failure instead of fault

    const int*   ent_tok  = (const int*)  d_in[0];
    const int*   ent_len  = (const int*)  d_in[1];
    const int*   at_tok   = (const int*)  d_in[3];
    const int*   at_len   = (const int*)  d_in[4];
    const float* emb      = (const float*)d_in[6];
    const float* Wih_ent  = (const float*)d_in[7];
    const float* Whh_ent  = (const float*)d_in[8];
    const float* bih_ent  = (const float*)d_in[9];
    const float* bhh_ent  = (const float*)d_in[10];
    const float* Wih_attr = (const float*)d_in[11];
    const float* Whh_attr = (const float*)d_in[12];
    const float* bih_attr = (const float*)d_in[13];
    const float* bhh_attr = (const float*)d_in[14];
    const float* Wfc      = (const float*)d_in[15];
    const float* bfc      = (const float*)d_in[16];
    const float* Wg       = (const float*)d_in[17];
    const float* a_src    = (const float*)d_in[18];
    const float* a_dst    = (const float*)d_in[19];
    float* out = (float*)d_out;

    char* p = (char*)d_ws;
    bf16_t* embB  = (bf16_t*)p; p += SZ_EMBB;
    bf16_t* proj  = (bf16_t*)p; p += SZ_PROJ;
    bf16_t* hAtt[2];
    hAtt[0] = (bf16_t*)p; p += SZ_HATT;
    hAtt[1] = (bf16_t*)p; p += SZ_HATT;
    bf16_t* hEnt   = (bf16_t*)p; p += SZ_HENT;
    bf16_t* hEnt2  = (bf16_t*)p; p += SZ_HENT;
    bf16_t* Wih3   = (bf16_t*)p; p += SZ_WIH3;
    bf16_t* Whh3_a = (bf16_t*)p; p += SZ_WHH3E;
    bf16_t* Whh3_e = (bf16_t*)p; p += SZ_WHH3E;
    bf16_t* WfcB   = (bf16_t*)p; p += SZ_WFC;
    bf16_t* WgB    = (bf16_t*)p; p += SZ_WG;
    float*  asW    = (float*)p;  p += SZ_AW;
    float*  adW    = (float*)p;  p += SZ_AW;
    float*  es     = (float*)p;  p += SZ_VEC;
    float*  ed     = (float*)p;  p += SZ_VEC;
    bf16_t* nodes  = embB;       // overlay: embB+proj dead after GRU loops
    bf16_t* mixed  = hAtt[0];    // overlay: hAtt dead after fc_nodes_esed

    // zero h ping-pong buffers (h0 = 0; pad cols must stay 0)
    hipMemsetAsync(hAtt[0], 0, SZ_HATT, stream);
    hipMemsetAsync(hAtt[1], 0, SZ_HATT, stream);
    hipMemsetAsync(hEnt,  0, SZ_HENT, stream);
    hipMemsetAsync(hEnt2, 0, SZ_HENT, stream);

    // prep (both GRUs now use the INTERLEAVED n=3j+g layout)
    convert_emb_kernel<<<dim3((V_ * 40 + 255) / 256), 256, 0, stream>>>(emb, embB);
    build_w3i_kernel<<<dim3(HDIM * KPAD / 256), 256, 0, stream>>>(Wih_attr, Wih3);
    build_w3i_kernel<<<dim3(HDIM * KPAD / 256), 256, 0, stream>>>(Whh_attr, Whh3_a);
    build_w3i_kernel<<<dim3(HDIM * KPAD / 256), 256, 0, stream>>>(Whh_ent, Whh3_e);
    build_wfc_kernel<<<dim3(HDIM * KPAD / 256), 256, 0, stream>>>(Wfc, WfcB);
    build_wg_kernel<<<dim3(HDIM * HDIM / 256), 256, 0, stream>>>(Wg, WgB);
    asw_kernel<<<dim3(HDIM / 256), 256, 0, stream>>>(Wg, a_src, a_dst, asW, adW);

    // attr vocab projection (interleaved): proj[v] = embB[v] @ Wih3i_attr^T
    mfma_gemm<0><<<dim3(VP / 128, PROJW / 128), 256, 0, stream>>>(
        embB, Wih3, proj, KPAD, KPAD, PROJW, KPAD);

    // attr GRU: T=4 fused steps (final h in hAtt[0])
    for (int t = 0; t < TA_; ++t)
        gru_attr_fused<<<dim3(GA / 64), 256, 0, stream>>>(
            hAtt[t & 1], hAtt[(t + 1) & 1], Whh3_a, proj, at_tok, at_len,
            bih_attr, bhh_attr, TA_, t);

    // ent vocab projection (interleaved); overwrite proj
    build_w3i_kernel<<<dim3(HDIM * KPAD / 256), 256, 0, stream>>>(Wih_ent, Wih3);
    mfma_gemm<0><<<dim3(VP / 128, PROJW / 128), 256, 0, stream>>>(
        embB, Wih3, proj, KPAD, KPAD, PROJW, KPAD);

    // ent GRU: 8 fused GEMM+epilogue step launches, ping-pong h
    bf16_t* hb[2] = { hEnt, hEnt2 };
    for (int t = 0; t < TE_; ++t)
        gru_step_fused<<<dim3(G / 128, 8), 512, 0, stream>>>(
            hb[t & 1], hb[(t + 1) & 1], Whh3_e, proj, ent_tok, ent_len,
            bih_ent, bhh_ent, TE_, t);

    // nodes = relu(h @ Wfc^T + bfc) with fused es/ed
    fc_nodes_esed<<<dim3(MROWS / 64), 256, 0, stream>>>(
        hEnt, hAtt[0], WfcB, bfc, asW, adW, nodes, es, ed);

    // row-0 softmax + node mixing
    attn_mix_kernel<<<dim3(G), 256, 0, stream>>>(nodes, es, ed, mixed);

    // out = elu(mixed @ Wg^T)
    mfma_gemm<2><<<dim3(G / 128, HDIM / 128), 256, 0, stream>>>(
        mixed, WgB, out, HDIM, HDIM, HDIM, HDIM);
}

// Round 5
// 779.600 us; speedup vs baseline: 1.3698x; 1.3698x over previous
//
#include <hip/hip_runtime.h>
#include <math.h>

namespace {

typedef unsigned short bf16_t;
typedef __bf16  bf16x8_t __attribute__((ext_vector_type(8)));
typedef float   f32x4_t  __attribute__((ext_vector_type(4)));
typedef unsigned int u32x4 __attribute__((ext_vector_type(4)));

constexpr int G     = 4096;      // BS*E
constexpr int GA    = 32768;     // G*A
constexpr int WDIM  = 300;
constexpr int KPAD  = 320;
constexpr int HDIM  = 1024;
constexpr int NNODE = 9;
constexpr int MROWS = G * NNODE; // 36864
constexpr int TE_   = 8;
constexpr int TA_   = 4;
constexpr int V_    = 30522;
constexpr int VP    = 30592;     // 239*128
constexpr int PROJW = 1024;

__device__ __forceinline__ float bf2f(bf16_t b) {
    union { unsigned int u; float f; } v; v.u = ((unsigned int)b) << 16; return v.f;
}
__device__ __forceinline__ bf16_t f2bf(float f) {
    union { float f; unsigned int u; } v; v.f = f;
    unsigned int r = v.u + 0x7FFFu + ((v.u >> 16) & 1u);   // RNE
    return (bf16_t)(r >> 16);
}

// =====================================================================
// Generic 128x128-tile bf16 MFMA GEMM (validated R3/R4): C = A[M,K] @ B[N,K]^T
// MODE 0: C bf16 (vocab projection)   MODE 2: C fp32 with elu (final out)
// =====================================================================
template<int MODE>
__global__ __launch_bounds__(256)
void mfma_gemm(const bf16_t* __restrict__ A, const bf16_t* __restrict__ B,
               void* __restrict__ Cv, int lda, int ldb, int ldc, int K)
{
    __shared__ bf16_t As[128 * 32];
    __shared__ bf16_t Bs[128 * 32];

    const int tid  = threadIdx.x;
    const int w    = tid >> 6;
    const int lane = tid & 63;
    const int wr = w >> 1, wc = w & 1;
    const int lr = lane & 15;
    const int lk = lane >> 4;
    const int m0 = blockIdx.x * 128, n0 = blockIdx.y * 128;

    const int r0 = tid >> 2;
    const int cc = (tid & 3) * 8;
    const bf16_t* Arow0 = A + (size_t)(m0 + r0) * lda + cc;
    const bf16_t* Arow1 = Arow0 + (size_t)64 * lda;
    const bf16_t* Brow0 = B + (size_t)(n0 + r0) * ldb + cc;
    const bf16_t* Brow1 = Brow0 + (size_t)64 * ldb;

    f32x4_t acc[4][4];
#pragma unroll
    for (int i = 0; i < 4; ++i)
#pragma unroll
        for (int j = 0; j < 4; ++j) acc[i][j] = {0.f, 0.f, 0.f, 0.f};

    for (int k0 = 0; k0 < K; k0 += 32) {
        const uint4 a0 = *(const uint4*)(Arow0 + k0);
        const uint4 a1 = *(const uint4*)(Arow1 + k0);
        const uint4 b0 = *(const uint4*)(Brow0 + k0);
        const uint4 b1 = *(const uint4*)(Brow1 + k0);
        __syncthreads();
        *(uint4*)&As[r0 * 32 + cc]        = a0;
        *(uint4*)&As[(r0 + 64) * 32 + cc] = a1;
        *(uint4*)&Bs[r0 * 32 + cc]        = b0;
        *(uint4*)&Bs[(r0 + 64) * 32 + cc] = b1;
        __syncthreads();

        bf16x8_t af[4], bfr[4];
#pragma unroll
        for (int i = 0; i < 4; ++i) {
            af[i]  = *(const bf16x8_t*)&As[(wr * 64 + i * 16 + lr) * 32 + lk * 8];
            bfr[i] = *(const bf16x8_t*)&Bs[(wc * 64 + i * 16 + lr) * 32 + lk * 8];
        }
#pragma unroll
        for (int mi = 0; mi < 4; ++mi)
#pragma unroll
            for (int ni = 0; ni < 4; ++ni)
                acc[mi][ni] = __builtin_amdgcn_mfma_f32_16x16x32_bf16(
                    af[mi], bfr[ni], acc[mi][ni], 0, 0, 0);
    }

#pragma unroll
    for (int mi = 0; mi < 4; ++mi) {
#pragma unroll
        for (int ni = 0; ni < 4; ++ni) {
            const int n = n0 + wc * 64 + ni * 16 + lr;
#pragma unroll
            for (int r = 0; r < 4; ++r) {
                const int m = m0 + wr * 64 + mi * 16 + lk * 4 + r;
                const float v = acc[mi][ni][r];
                if (MODE == 0)
                    ((bf16_t*)Cv)[(size_t)m * ldc + n] = f2bf(v);
                else
                    ((float*)Cv)[(size_t)m * ldc + n] = v > 0.f ? v : expm1f(v);
            }
        }
    }
}

// =====================================================================
// GRU step (R13-validated; R15: now used for BOTH ent and attr).
// One launch per step; fused GEMM + gate epilogue.
// gates[M x 960] = h @ Whh3i^T, tile M=128 x N=120 (interleaved n=3j+g),
// grid (M/128, 8), 512 thr (2Mx4N waves). Scatter guarded col<120 (R12
// race lesson). Grid x = m-block => bid%8 = mb%8: the 8 nb-siblings that
// share an A-tile land on the SAME XCD -> A re-read served by its L2.
// R14 post-mortem: the attr-specific variant (64-row block, nb loop
// inside, gates via LDS) serialized staging behind 160 barriers with no
// inter-block pipelining -> 150us/step. This kernel at 2048 blocks gives
// 2 resident blocks/CU with 4 queued behind them -> staging overlaps
// compute across blocks.
// =====================================================================
__global__ __launch_bounds__(512)
void gru_step_fused(const bf16_t* __restrict__ hin,     // [M][KPAD]
                    bf16_t* __restrict__ hout,          // [M][KPAD]
                    const bf16_t* __restrict__ Whh3i,   // [1024][320] n=3j+g
                    const bf16_t* __restrict__ proj,    // [VP][1024]  n=3j+g
                    const int* __restrict__ tokens,
                    const int* __restrict__ lengths,
                    const float* __restrict__ bih, const float* __restrict__ bhh,
                    int T, int t)
{
    constexpr int GSTRF = 123;               // odd f32 stride; 120 used cols
    __shared__ __align__(16) bf16_t As[128 * 32];   // 8 KB
    __shared__ __align__(16) bf16_t Bs[128 * 32];   // 8 KB
    __shared__ float gsm[128 * GSTRF];              // 61.5 KB

    const int tid = threadIdx.x;
    const int w = tid >> 6, lane = tid & 63;
    const int lr = lane & 15, lk = lane >> 4;
    const int wr = w >> 2, wc = w & 3;       // 2 (M) x 4 (N) waves
    const int m0 = blockIdx.x * 128;
    const int nb = blockIdx.y;               // 0..7
    const int n0 = nb * 120;

    const int sr = tid >> 2, sc = (tid & 3) * 8;
    const bf16_t* Ap = hin   + (size_t)(m0 + sr) * KPAD + sc;
    const bf16_t* Bp = Whh3i + (size_t)(n0 + sr) * KPAD + sc;

    f32x4_t acc[4][2];
#pragma unroll
    for (int mi = 0; mi < 4; ++mi)
#pragma unroll
        for (int ni = 0; ni < 2; ++ni) acc[mi][ni] = {0.f, 0.f, 0.f, 0.f};

    for (int k0 = 0; k0 < KPAD; k0 += 32) {
        const uint4 av = *(const uint4*)(Ap + k0);
        const uint4 bv = *(const uint4*)(Bp + k0);
        __syncthreads();
        *(uint4*)&As[sr * 32 + sc] = av;
        *(uint4*)&Bs[sr * 32 + sc] = bv;
        __syncthreads();

        bf16x8_t af[4], bfr[2];
#pragma unroll
        for (int mi = 0; mi < 4; ++mi)
            af[mi] = *(const bf16x8_t*)&As[(wr * 64 + mi * 16 + lr) * 32 + lk * 8];
#pragma unroll
        for (int ni = 0; ni < 2; ++ni)
            bfr[ni] = *(const bf16x8_t*)&Bs[(wc * 32 + ni * 16 + lr) * 32 + lk * 8];
#pragma unroll
        for (int mi = 0; mi < 4; ++mi)
#pragma unroll
            for (int ni = 0; ni < 2; ++ni)
                acc[mi][ni] = __builtin_amdgcn_mfma_f32_16x16x32_bf16(
                    af[mi], bfr[ni], acc[mi][ni], 0, 0, 0);
    }

    // scatter wave tiles to gates LDS (row = M, col = N); cols >= 120 are
    // the B-stage overlap belonging to the next nb block — DO NOT scatter
#pragma unroll
    for (int ni = 0; ni < 2; ++ni) {
        const int col = wc * 32 + ni * 16 + lr;
        if (col < 120) {
#pragma unroll
            for (int mi = 0; mi < 4; ++mi)
#pragma unroll
                for (int r = 0; r < 4; ++r)
                    gsm[(wr * 64 + mi * 16 + lk * 4 + r) * GSTRF + col]
                        = acc[mi][ni][r];
        }
    }
    __syncthreads();

    // ---- fused GRU epilogue: thread -> (row ml, quarter q), 10 j each ----
    const int ml = tid >> 2, q = tid & 3;
    if (nb == 7 && q >= 2) return;           // j >= 300 (boundary is exact)
    const int m  = m0 + ml;
    const int jb = nb * 40 + q * 10;
    int len = lengths[m]; if (len < 1) len = 1;
    const bool act = (t < len);
    const int tok = tokens[(size_t)m * T + t];

    const unsigned int* xpp =
        (const unsigned int*)(proj + (size_t)tok * PROJW + n0 + q * 30);
    unsigned int xw[15];
#pragma unroll
    for (int i = 0; i < 15; ++i) xw[i] = xpp[i];

    const unsigned int* hop = (const unsigned int*)(hin + (size_t)m * KPAD + jb);
    unsigned int hw[5];
#pragma unroll
    for (int i = 0; i < 5; ++i) hw[i] = hop[i];

    unsigned int ow[5];
#pragma unroll
    for (int u = 0; u < 10; ++u) {
        const int j = jb + u;
        const bf16_t hob = (bf16_t)((u & 1) ? (hw[u >> 1] >> 16) : (hw[u >> 1] & 0xffff));
        const float hold = bf2f(hob);
        float hv = hold;
        if (act) {
            const int e0 = 3 * u;
            const float xr = bf2f((bf16_t)((e0 & 1)       ? (xw[e0 >> 1] >> 16)       : (xw[e0 >> 1] & 0xffff)));
            const float xz = bf2f((bf16_t)(((e0 + 1) & 1) ? (xw[(e0 + 1) >> 1] >> 16) : (xw[(e0 + 1) >> 1] & 0xffff)));
            const float xn = bf2f((bf16_t)(((e0 + 2) & 1) ? (xw[(e0 + 2) >> 1] >> 16) : (xw[(e0 + 2) >> 1] & 0xffff)));
            const int nl = q * 30 + 3 * u;
            const float g0 = gsm[ml * GSTRF + nl];
            const float g1 = gsm[ml * GSTRF + nl + 1];
            const float g2 = gsm[ml * GSTRF + nl + 2];
            const float rr = 1.f / (1.f + expf(-(g0 + xr + bih[j] + bhh[j])));
            const float zz = 1.f / (1.f + expf(-(g1 + xz + bih[WDIM + j] + bhh[WDIM + j])));
            const float nn = tanhf(xn + bih[2 * WDIM + j] + rr * (g2 + bhh[2 * WDIM + j]));
            hv = (1.f - zz) * nn + zz * hold;
        }
        const bf16_t hb_ = f2bf(hv);
        if ((u & 1) == 0) ow[u >> 1] = hb_;
        else              ow[u >> 1] |= ((unsigned int)hb_) << 16;
    }
    unsigned int* outp = (unsigned int*)(hout + (size_t)m * KPAD + jb);
#pragma unroll
    for (int i = 0; i < 5; ++i) outp[i] = ow[i];
}

// =====================================================================
// FC + relu -> nodes (bf16) with FUSED es/ed (R6-validated).
// =====================================================================
__global__ __launch_bounds__(256)
void fc_nodes_esed(const bf16_t* __restrict__ hEnt, const bf16_t* __restrict__ hAtt,
                   const bf16_t* __restrict__ WfcB, const float* __restrict__ bfc,
                   const float* __restrict__ asW, const float* __restrict__ adW,
                   bf16_t* __restrict__ nodes, float* __restrict__ es, float* __restrict__ ed)
{
    constexpr int ASTR = 328;
    __shared__ bf16_t As[64 * ASTR];          // 41 KB
    __shared__ bf16_t Bs[64 * 32];            // 4 KB
    __shared__ const bf16_t* rowp[64];

    const int tid = threadIdx.x;
    const int w = tid >> 6, lane = tid & 63;
    const int lr = lane & 15, lk = lane >> 4;
    const int m0 = blockIdx.x * 64;

    if (tid < 64) {
        const int m = m0 + tid;
        const int g = m / NNODE, i = m - g * NNODE;
        rowp[tid] = (i == 0) ? (hEnt + (size_t)g * KPAD)
                             : (hAtt + (size_t)(g * 8 + (i - 1)) * KPAD);
    }
    __syncthreads();

#pragma unroll
    for (int it = 0; it < 10; ++it) {
        const int i = tid + 256 * it;
        const int row = i / 40, c8 = (i - row * 40) * 8;
        const uint4 v = *(const uint4*)(rowp[row] + c8);
        *(uint4*)&As[row * ASTR + c8] = v;
    }
    __syncthreads();

    float esa[4] = {0.f, 0.f, 0.f, 0.f};
    float eda[4] = {0.f, 0.f, 0.f, 0.f};

    for (int nt = 0; nt < 16; ++nt) {
        const int n0 = nt * 64;
        f32x4_t acc[4];
#pragma unroll
        for (int ni = 0; ni < 4; ++ni) acc[ni] = {0.f, 0.f, 0.f, 0.f};

        for (int k0 = 0; k0 < KPAD; k0 += 32) {
            const int rr_ = tid >> 2, c8 = (tid & 3) * 8;
            const uint4 bv = *(const uint4*)(WfcB + (size_t)(n0 + rr_) * KPAD + k0 + c8);
            __syncthreads();
            *(uint4*)&Bs[rr_ * 32 + c8] = bv;
            __syncthreads();

            const bf16x8_t af = *(const bf16x8_t*)&As[(w * 16 + lr) * ASTR + k0 + lk * 8];
#pragma unroll
            for (int ni = 0; ni < 4; ++ni) {
                const bf16x8_t bfr = *(const bf16x8_t*)&Bs[(ni * 16 + lr) * 32 + lk * 8];
                acc[ni] = __builtin_amdgcn_mfma_f32_16x16x32_bf16(af, bfr, acc[ni], 0, 0, 0);
            }
        }

#pragma unroll
        for (int ni = 0; ni < 4; ++ni) {
            const int n = n0 + ni * 16 + lr;
            const float aw = asW[n], dw = adW[n], bb = bfc[n];
#pragma unroll
            for (int r = 0; r < 4; ++r) {
                float v = acc[ni][r] + bb;
                v = v > 0.f ? v : 0.f;
                const int m = m0 + w * 16 + lk * 4 + r;
                nodes[(size_t)m * HDIM + n] = f2bf(v);
                esa[r] = fmaf(v, aw, esa[r]);
                eda[r] = fmaf(v, dw, eda[r]);
            }
        }
    }

    // reduce across the 16 lr lanes
#pragma unroll
    for (int r = 0; r < 4; ++r) {
        float s = esa[r], d = eda[r];
#pragma unroll
        for (int mask = 1; mask < 16; mask <<= 1) {
            s += __shfl_xor(s, mask, 64);
            d += __shfl_xor(d, mask, 64);
        }
        if (lr == 0) {
            const int m = m0 + w * 16 + lk * 4 + r;
            es[m] = s; ed[m] = d;
        }
    }
}

// =====================================================================
// Prep kernels
// =====================================================================
__global__ __launch_bounds__(256)
void convert_emb_kernel(const float* __restrict__ emb, bf16_t* __restrict__ embB)
{
    const int idx = blockIdx.x * 256 + threadIdx.x;    // over V_*40
    if (idx >= V_ * 40) return;
    const int row = idx / 40, c8 = (idx - row * 40) * 8;
    bf16_t o[8];
#pragma unroll
    for (int e = 0; e < 8; ++e) {
        const int c = c8 + e;
        o[e] = (c < WDIM) ? f2bf(emb[(size_t)row * WDIM + c]) : (bf16_t)0;
    }
    *(ushort4*)(embB + (size_t)row * KPAD + c8)     = *(ushort4*)&o[0];
    *(ushort4*)(embB + (size_t)row * KPAD + c8 + 4) = *(ushort4*)&o[4];
}

// W [3*300][300] fp32 -> dst[1024][320] bf16, INTERLEAVED rows n = 3*j + g
__global__ __launch_bounds__(256)
void build_w3i_kernel(const float* __restrict__ W, bf16_t* __restrict__ dst)
{
    const int idx = blockIdx.x * 256 + threadIdx.x;    // over 1024*320
    if (idx >= HDIM * KPAD) return;
    const int n = idx / KPAD, k = idx - n * KPAD;
    float v = 0.f;
    if (n < 960) {
        const int j = n / 3, g = n - j * 3;
        if (j < WDIM && k < WDIM)
            v = W[(size_t)(g * WDIM + j) * WDIM + k];
    }
    dst[idx] = f2bf(v);
}

__global__ __launch_bounds__(256)
void build_wfc_kernel(const float* __restrict__ Wfc, bf16_t* __restrict__ Wb)
{
    const int idx = blockIdx.x * 256 + threadIdx.x;    // over 1024*320
    if (idx >= HDIM * KPAD) return;
    const int n = idx / KPAD, k = idx - n * KPAD;
    Wb[idx] = f2bf(k < WDIM ? Wfc[(size_t)n * WDIM + k] : 0.f);
}

__global__ __launch_bounds__(256)
void build_wg_kernel(const float* __restrict__ Wg, bf16_t* __restrict__ Wb)
{
    const int idx = blockIdx.x * 256 + threadIdx.x;    // over 1024*1024
    Wb[idx] = f2bf(Wg[idx]);
}

// asW = a_src @ Wg, adW = a_dst @ Wg
__global__ __launch_bounds__(256)
void asw_kernel(const float* __restrict__ Wg,
                const float* __restrict__ a_src, const float* __restrict__ a_dst,
                float* __restrict__ asW, float* __restrict__ adW)
{
    const int k = blockIdx.x * 256 + threadIdx.x;
    float s = 0.f, d = 0.f;
    for (int n = 0; n < HDIM; ++n) {
        const float w = Wg[(size_t)n * HDIM + k];
        s = fmaf(a_src[n], w, s);
        d = fmaf(a_dst[n], w, d);
    }
    asW[k] = s; adW[k] = d;
}

// Row-0 star attention -> mixed[g] = sum_j alpha_j * nodes[g*9+j] (bf16)
__global__ __launch_bounds__(256)
void attn_mix_kernel(const bf16_t* __restrict__ nodes,
                     const float* __restrict__ es, const float* __restrict__ ed,
                     bf16_t* __restrict__ mixed)
{
    const int g = blockIdx.x;
    const float e0 = es[(size_t)g * NNODE];
    const float* edg = ed + (size_t)g * NNODE;

    float w[NNODE], mx = -1e30f;
#pragma unroll
    for (int j = 0; j < NNODE; ++j) {
        float v = e0 + edg[j];
        v = v >= 0.f ? v : 0.2f * v;
        w[j] = v; mx = fmaxf(mx, v);
    }
    float denom = 0.f;
#pragma unroll
    for (int j = 0; j < NNODE; ++j) { w[j] = expf(w[j] - mx); denom += w[j]; }
    const float inv = 1.f / denom;

    const int c = threadIdx.x * 4;
    float4 acc = {0.f, 0.f, 0.f, 0.f};
#pragma unroll
    for (int j = 0; j < NNODE; ++j) {
        const float a = w[j] * inv;
        const ushort4 h4 = *(const ushort4*)(nodes + (size_t)(g * NNODE + j) * HDIM + c);
        acc.x = fmaf(a, bf2f(h4.x), acc.x);
        acc.y = fmaf(a, bf2f(h4.y), acc.y);
        acc.z = fmaf(a, bf2f(h4.z), acc.z);
        acc.w = fmaf(a, bf2f(h4.w), acc.w);
    }
    ushort4 o;
    o.x = f2bf(acc.x); o.y = f2bf(acc.y); o.z = f2bf(acc.z); o.w = f2bf(acc.w);
    *(ushort4*)(mixed + (size_t)g * HDIM + c) = o;
}

// -------- workspace layout (~134 MiB; 157 MiB known-safe) --------
constexpr size_t SZ_EMBB  = (size_t)VP * KPAD * sizeof(bf16_t);      // 19.58 MB
constexpr size_t SZ_PROJ  = (size_t)VP * PROJW * sizeof(bf16_t);     // 62.65 MB
constexpr size_t SZ_HATT  = (size_t)GA * KPAD * sizeof(bf16_t);      // 20.97 MB x2
constexpr size_t SZ_HENT  = (size_t)G * KPAD * sizeof(bf16_t);       //  2.62 MB x2
constexpr size_t SZ_WIH3  = (size_t)HDIM * KPAD * sizeof(bf16_t);
constexpr size_t SZ_WHH3E = (size_t)HDIM * KPAD * sizeof(bf16_t);    //  0.66 MB x2 (1024 rows)
constexpr size_t SZ_WFC   = (size_t)HDIM * KPAD * sizeof(bf16_t);
constexpr size_t SZ_WG    = (size_t)HDIM * HDIM * sizeof(bf16_t);
constexpr size_t SZ_AW    = (size_t)HDIM * sizeof(float);
constexpr size_t SZ_VEC   = (size_t)MROWS * sizeof(float);
constexpr size_t SZ_NODE  = (size_t)MROWS * HDIM * sizeof(bf16_t);   // 75.5 MB
constexpr size_t SZ_MIX   = (size_t)G * HDIM * sizeof(bf16_t);
constexpr size_t WS_NEED  = SZ_EMBB + SZ_PROJ + 2 * SZ_HATT + 2 * SZ_HENT +
                            SZ_WIH3 + 2 * SZ_WHH3E + SZ_WFC + SZ_WG +
                            2 * SZ_AW + 2 * SZ_VEC;
static_assert(SZ_NODE <= SZ_EMBB + SZ_PROJ, "nodes overlays embB+proj");
static_assert(SZ_MIX  <= 2 * SZ_HATT,       "mixed overlays hAtt pair");

} // namespace

extern "C" void kernel_launch(void* const* d_in, const int* in_sizes, int n_in,
                              void* d_out, int out_size, void* d_ws, size_t ws_size,
                              hipStream_t stream)
{
    (void)in_sizes; (void)n_in; (void)out_size;
    if (ws_size < WS_NEED) return;   // clean absmax failure instead of fault

    const int*   ent_tok  = (const int*)  d_in[0];
    const int*   ent_len  = (const int*)  d_in[1];
    const int*   at_tok   = (const int*)  d_in[3];
    const int*   at_len   = (const int*)  d_in[4];
    const float* emb      = (const float*)d_in[6];
    const float* Wih_ent  = (const float*)d_in[7];
    const float* Whh_ent  = (const float*)d_in[8];
    const float* bih_ent  = (const float*)d_in[9];
    const float* bhh_ent  = (const float*)d_in[10];
    const float* Wih_attr = (const float*)d_in[11];
    const float* Whh_attr = (const float*)d_in[12];
    const float* bih_attr = (const float*)d_in[13];
    const float* bhh_attr = (const float*)d_in[14];
    const float* Wfc      = (const float*)d_in[15];
    const float* bfc      = (const float*)d_in[16];
    const float* Wg       = (const float*)d_in[17];
    const float* a_src    = (const float*)d_in[18];
    const float* a_dst    = (const float*)d_in[19];
    float* out = (float*)d_out;

    char* p = (char*)d_ws;
    bf16_t* embB  = (bf16_t*)p; p += SZ_EMBB;
    bf16_t* proj  = (bf16_t*)p; p += SZ_PROJ;
    bf16_t* hAtt[2];
    hAtt[0] = (bf16_t*)p; p += SZ_HATT;
    hAtt[1] = (bf16_t*)p; p += SZ_HATT;
    bf16_t* hEnt   = (bf16_t*)p; p += SZ_HENT;
    bf16_t* hEnt2  = (bf16_t*)p; p += SZ_HENT;
    bf16_t* Wih3   = (bf16_t*)p; p += SZ_WIH3;
    bf16_t* Whh3_a = (bf16_t*)p; p += SZ_WHH3E;
    bf16_t* Whh3_e = (bf16_t*)p; p += SZ_WHH3E;
    bf16_t* WfcB   = (bf16_t*)p; p += SZ_WFC;
    bf16_t* WgB    = (bf16_t*)p; p += SZ_WG;
    float*  asW    = (float*)p;  p += SZ_AW;
    float*  adW    = (float*)p;  p += SZ_AW;
    float*  es     = (float*)p;  p += SZ_VEC;
    float*  ed     = (float*)p;  p += SZ_VEC;
    bf16_t* nodes  = embB;       // overlay: embB+proj dead after GRU loops
    bf16_t* mixed  = hAtt[0];    // overlay: hAtt dead after fc_nodes_esed

    // zero h ping-pong buffers (h0 = 0; pad cols must stay 0)
    hipMemsetAsync(hAtt[0], 0, SZ_HATT, stream);
    hipMemsetAsync(hAtt[1], 0, SZ_HATT, stream);
    hipMemsetAsync(hEnt,  0, SZ_HENT, stream);
    hipMemsetAsync(hEnt2, 0, SZ_HENT, stream);

    // prep (both GRUs use the INTERLEAVED n=3j+g layout)
    convert_emb_kernel<<<dim3((V_ * 40 + 255) / 256), 256, 0, stream>>>(emb, embB);
    build_w3i_kernel<<<dim3(HDIM * KPAD / 256), 256, 0, stream>>>(Wih_attr, Wih3);
    build_w3i_kernel<<<dim3(HDIM * KPAD / 256), 256, 0, stream>>>(Whh_attr, Whh3_a);
    build_w3i_kernel<<<dim3(HDIM * KPAD / 256), 256, 0, stream>>>(Whh_ent, Whh3_e);
    build_wfc_kernel<<<dim3(HDIM * KPAD / 256), 256, 0, stream>>>(Wfc, WfcB);
    build_wg_kernel<<<dim3(HDIM * HDIM / 256), 256, 0, stream>>>(Wg, WgB);
    asw_kernel<<<dim3(HDIM / 256), 256, 0, stream>>>(Wg, a_src, a_dst, asW, adW);

    // attr vocab projection (interleaved): proj[v] = embB[v] @ Wih3i_attr^T
    mfma_gemm<0><<<dim3(VP / 128, PROJW / 128), 256, 0, stream>>>(
        embB, Wih3, proj, KPAD, KPAD, PROJW, KPAD);

    // attr GRU: T=4 fused GEMM+epilogue steps, grid 256x8 = 2048 blocks
    // (final h in hAtt[0])
    for (int t = 0; t < TA_; ++t)
        gru_step_fused<<<dim3(GA / 128, 8), 512, 0, stream>>>(
            hAtt[t & 1], hAtt[(t + 1) & 1], Whh3_a, proj, at_tok, at_len,
            bih_attr, bhh_attr, TA_, t);

    // ent vocab projection (interleaved); overwrite proj
    build_w3i_kernel<<<dim3(HDIM * KPAD / 256), 256, 0, stream>>>(Wih_ent, Wih3);
    mfma_gemm<0><<<dim3(VP / 128, PROJW / 128), 256, 0, stream>>>(
        embB, Wih3, proj, KPAD, KPAD, PROJW, KPAD);

    // ent GRU: 8 fused GEMM+epilogue step launches, ping-pong h
    bf16_t* hb[2] = { hEnt, hEnt2 };
    for (int t = 0; t < TE_; ++t)
        gru_step_fused<<<dim3(G / 128, 8), 512, 0, stream>>>(
            hb[t & 1], hb[(t + 1) & 1], Whh3_e, proj, ent_tok, ent_len,
            bih_ent, bhh_ent, TE_, t);

    // nodes = relu(h @ Wfc^T + bfc) with fused es/ed
    fc_nodes_esed<<<dim3(MROWS / 64), 256, 0, stream>>>(
        hEnt, hAtt[0], WfcB, bfc, asW, adW, nodes, es, ed);

    // row-0 softmax + node mixing
    attn_mix_kernel<<<dim3(G), 256, 0, stream>>>(nodes, es, ed, mixed);

    // out = elu(mixed @ Wg^T)
    mfma_gemm<2><<<dim3(G / 128, HDIM / 128), 256, 0, stream>>>(
        mixed, WgB, out, HDIM, HDIM, HDIM, HDIM);
}

// Round 6
// 767.737 us; speedup vs baseline: 1.3910x; 1.0155x over previous
//
#include <hip/hip_runtime.h>
#include <math.h>

namespace {

typedef unsigned short bf16_t;
typedef __bf16  bf16x8_t __attribute__((ext_vector_type(8)));
typedef float   f32x4_t  __attribute__((ext_vector_type(4)));
typedef unsigned int u32x4 __attribute__((ext_vector_type(4)));

constexpr int G     = 4096;      // BS*E
constexpr int GA    = 32768;     // G*A
constexpr int WDIM  = 300;
constexpr int KPAD  = 320;
constexpr int HDIM  = 1024;
constexpr int NNODE = 9;
constexpr int MROWS = G * NNODE; // 36864
constexpr int TE_   = 8;
constexpr int TA_   = 4;
constexpr int V_    = 30522;
constexpr int VP    = 30592;     // 239*128
constexpr int PROJW = 1024;

__device__ __forceinline__ float bf2f(bf16_t b) {
    union { unsigned int u; float f; } v; v.u = ((unsigned int)b) << 16; return v.f;
}
__device__ __forceinline__ bf16_t f2bf(float f) {
    union { float f; unsigned int u; } v; v.f = f;
    unsigned int r = v.u + 0x7FFFu + ((v.u >> 16) & 1u);   // RNE
    return (bf16_t)(r >> 16);
}

// =====================================================================
// Generic 128x128-tile bf16 MFMA GEMM: C = A[M,K] @ B[N,K]^T
// MODE 0: C bf16 (vocab projection)   MODE 2: C fp32 with elu (final out)
// R16: LDS row stride 32 -> 40 bf16 (80 B). At stride 32, the 16 lr
// lanes of each ds_read_b128 alias 8 addresses per bank (8-way
// serialize); stride 40 makes the starts distinct -> 2-way (free).
// =====================================================================
template<int MODE>
__global__ __launch_bounds__(256)
void mfma_gemm(const bf16_t* __restrict__ A, const bf16_t* __restrict__ B,
               void* __restrict__ Cv, int lda, int ldb, int ldc, int K)
{
    constexpr int AST = 40;                  // padded LDS row stride (bf16)
    __shared__ __align__(16) bf16_t As[128 * AST];   // 10 KB
    __shared__ __align__(16) bf16_t Bs[128 * AST];   // 10 KB

    const int tid  = threadIdx.x;
    const int w    = tid >> 6;
    const int lane = tid & 63;
    const int wr = w >> 1, wc = w & 1;
    const int lr = lane & 15;
    const int lk = lane >> 4;
    const int m0 = blockIdx.x * 128, n0 = blockIdx.y * 128;

    const int r0 = tid >> 2;
    const int cc = (tid & 3) * 8;
    const bf16_t* Arow0 = A + (size_t)(m0 + r0) * lda + cc;
    const bf16_t* Arow1 = Arow0 + (size_t)64 * lda;
    const bf16_t* Brow0 = B + (size_t)(n0 + r0) * ldb + cc;
    const bf16_t* Brow1 = Brow0 + (size_t)64 * ldb;

    f32x4_t acc[4][4];
#pragma unroll
    for (int i = 0; i < 4; ++i)
#pragma unroll
        for (int j = 0; j < 4; ++j) acc[i][j] = {0.f, 0.f, 0.f, 0.f};

    for (int k0 = 0; k0 < K; k0 += 32) {
        const uint4 a0 = *(const uint4*)(Arow0 + k0);
        const uint4 a1 = *(const uint4*)(Arow1 + k0);
        const uint4 b0 = *(const uint4*)(Brow0 + k0);
        const uint4 b1 = *(const uint4*)(Brow1 + k0);
        __syncthreads();
        *(uint4*)&As[r0 * AST + cc]        = a0;
        *(uint4*)&As[(r0 + 64) * AST + cc] = a1;
        *(uint4*)&Bs[r0 * AST + cc]        = b0;
        *(uint4*)&Bs[(r0 + 64) * AST + cc] = b1;
        __syncthreads();

        bf16x8_t af[4], bfr[4];
#pragma unroll
        for (int i = 0; i < 4; ++i) {
            af[i]  = *(const bf16x8_t*)&As[(wr * 64 + i * 16 + lr) * AST + lk * 8];
            bfr[i] = *(const bf16x8_t*)&Bs[(wc * 64 + i * 16 + lr) * AST + lk * 8];
        }
#pragma unroll
        for (int mi = 0; mi < 4; ++mi)
#pragma unroll
            for (int ni = 0; ni < 4; ++ni)
                acc[mi][ni] = __builtin_amdgcn_mfma_f32_16x16x32_bf16(
                    af[mi], bfr[ni], acc[mi][ni], 0, 0, 0);
    }

#pragma unroll
    for (int mi = 0; mi < 4; ++mi) {
#pragma unroll
        for (int ni = 0; ni < 4; ++ni) {
            const int n = n0 + wc * 64 + ni * 16 + lr;
#pragma unroll
            for (int r = 0; r < 4; ++r) {
                const int m = m0 + wr * 64 + mi * 16 + lk * 4 + r;
                const float v = acc[mi][ni][r];
                if (MODE == 0)
                    ((bf16_t*)Cv)[(size_t)m * ldc + n] = f2bf(v);
                else
                    ((float*)Cv)[(size_t)m * ldc + n] = v > 0.f ? v : expm1f(v);
            }
        }
    }
}

// =====================================================================
// GRU step (R13-validated; used for BOTH ent and attr).
// One launch per step; fused GEMM + gate epilogue.
// gates[M x 960] = h @ Whh3i^T, tile M=128 x N=120 (interleaved n=3j+g),
// grid (M/128, 8), 512 thr (2Mx4N waves). Scatter guarded col<120 (R12
// race lesson). Grid x = m-block => bid%8 = mb%8: nb-siblings sharing an
// A-tile land on the same XCD -> A re-read served by its L2.
// =====================================================================
__global__ __launch_bounds__(512)
void gru_step_fused(const bf16_t* __restrict__ hin,     // [M][KPAD]
                    bf16_t* __restrict__ hout,          // [M][KPAD]
                    const bf16_t* __restrict__ Whh3i,   // [1024][320] n=3j+g
                    const bf16_t* __restrict__ proj,    // [VP][1024]  n=3j+g
                    const int* __restrict__ tokens,
                    const int* __restrict__ lengths,
                    const float* __restrict__ bih, const float* __restrict__ bhh,
                    int T, int t)
{
    constexpr int GSTRF = 123;               // odd f32 stride; 120 used cols
    __shared__ __align__(16) bf16_t As[128 * 32];   // 8 KB
    __shared__ __align__(16) bf16_t Bs[128 * 32];   // 8 KB
    __shared__ float gsm[128 * GSTRF];              // 61.5 KB

    const int tid = threadIdx.x;
    const int w = tid >> 6, lane = tid & 63;
    const int lr = lane & 15, lk = lane >> 4;
    const int wr = w >> 2, wc = w & 3;       // 2 (M) x 4 (N) waves
    const int m0 = blockIdx.x * 128;
    const int nb = blockIdx.y;               // 0..7
    const int n0 = nb * 120;

    const int sr = tid >> 2, sc = (tid & 3) * 8;
    const bf16_t* Ap = hin   + (size_t)(m0 + sr) * KPAD + sc;
    const bf16_t* Bp = Whh3i + (size_t)(n0 + sr) * KPAD + sc;

    f32x4_t acc[4][2];
#pragma unroll
    for (int mi = 0; mi < 4; ++mi)
#pragma unroll
        for (int ni = 0; ni < 2; ++ni) acc[mi][ni] = {0.f, 0.f, 0.f, 0.f};

    for (int k0 = 0; k0 < KPAD; k0 += 32) {
        const uint4 av = *(const uint4*)(Ap + k0);
        const uint4 bv = *(const uint4*)(Bp + k0);
        __syncthreads();
        *(uint4*)&As[sr * 32 + sc] = av;
        *(uint4*)&Bs[sr * 32 + sc] = bv;
        __syncthreads();

        bf16x8_t af[4], bfr[2];
#pragma unroll
        for (int mi = 0; mi < 4; ++mi)
            af[mi] = *(const bf16x8_t*)&As[(wr * 64 + mi * 16 + lr) * 32 + lk * 8];
#pragma unroll
        for (int ni = 0; ni < 2; ++ni)
            bfr[ni] = *(const bf16x8_t*)&Bs[(wc * 32 + ni * 16 + lr) * 32 + lk * 8];
#pragma unroll
        for (int mi = 0; mi < 4; ++mi)
#pragma unroll
            for (int ni = 0; ni < 2; ++ni)
                acc[mi][ni] = __builtin_amdgcn_mfma_f32_16x16x32_bf16(
                    af[mi], bfr[ni], acc[mi][ni], 0, 0, 0);
    }

    // scatter wave tiles to gates LDS (row = M, col = N); cols >= 120 are
    // the B-stage overlap belonging to the next nb block — DO NOT scatter
#pragma unroll
    for (int ni = 0; ni < 2; ++ni) {
        const int col = wc * 32 + ni * 16 + lr;
        if (col < 120) {
#pragma unroll
            for (int mi = 0; mi < 4; ++mi)
#pragma unroll
                for (int r = 0; r < 4; ++r)
                    gsm[(wr * 64 + mi * 16 + lk * 4 + r) * GSTRF + col]
                        = acc[mi][ni][r];
        }
    }
    __syncthreads();

    // ---- fused GRU epilogue: thread -> (row ml, quarter q), 10 j each ----
    const int ml = tid >> 2, q = tid & 3;
    if (nb == 7 && q >= 2) return;           // j >= 300 (boundary is exact)
    const int m  = m0 + ml;
    const int jb = nb * 40 + q * 10;
    int len = lengths[m]; if (len < 1) len = 1;
    const bool act = (t < len);
    const int tok = tokens[(size_t)m * T + t];

    const unsigned int* xpp =
        (const unsigned int*)(proj + (size_t)tok * PROJW + n0 + q * 30);
    unsigned int xw[15];
#pragma unroll
    for (int i = 0; i < 15; ++i) xw[i] = xpp[i];

    const unsigned int* hop = (const unsigned int*)(hin + (size_t)m * KPAD + jb);
    unsigned int hw[5];
#pragma unroll
    for (int i = 0; i < 5; ++i) hw[i] = hop[i];

    unsigned int ow[5];
#pragma unroll
    for (int u = 0; u < 10; ++u) {
        const int j = jb + u;
        const bf16_t hob = (bf16_t)((u & 1) ? (hw[u >> 1] >> 16) : (hw[u >> 1] & 0xffff));
        const float hold = bf2f(hob);
        float hv = hold;
        if (act) {
            const int e0 = 3 * u;
            const float xr = bf2f((bf16_t)((e0 & 1)       ? (xw[e0 >> 1] >> 16)       : (xw[e0 >> 1] & 0xffff)));
            const float xz = bf2f((bf16_t)(((e0 + 1) & 1) ? (xw[(e0 + 1) >> 1] >> 16) : (xw[(e0 + 1) >> 1] & 0xffff)));
            const float xn = bf2f((bf16_t)(((e0 + 2) & 1) ? (xw[(e0 + 2) >> 1] >> 16) : (xw[(e0 + 2) >> 1] & 0xffff)));
            const int nl = q * 30 + 3 * u;
            const float g0 = gsm[ml * GSTRF + nl];
            const float g1 = gsm[ml * GSTRF + nl + 1];
            const float g2 = gsm[ml * GSTRF + nl + 2];
            const float rr = 1.f / (1.f + expf(-(g0 + xr + bih[j] + bhh[j])));
            const float zz = 1.f / (1.f + expf(-(g1 + xz + bih[WDIM + j] + bhh[WDIM + j])));
            const float nn = tanhf(xn + bih[2 * WDIM + j] + rr * (g2 + bhh[2 * WDIM + j]));
            hv = (1.f - zz) * nn + zz * hold;
        }
        const bf16_t hb_ = f2bf(hv);
        if ((u & 1) == 0) ow[u >> 1] = hb_;
        else              ow[u >> 1] |= ((unsigned int)hb_) << 16;
    }
    unsigned int* outp = (unsigned int*)(hout + (size_t)m * KPAD + jb);
#pragma unroll
    for (int i = 0; i < 5; ++i) outp[i] = ow[i];
}

// =====================================================================
// R16: nodes = relu(h @ Wfc^T + bfc) as a PROPER 128x128 GEMM with a
// gathered A (128-entry LDS pointer table). Replaces fc_nodes_esed
// (81 us: 64-row tile re-staged WfcB behind 320 barriers, 7.4M LDS
// bank conflicts, MfmaUtil 11%). Grid (288, 8), 20 barriers/block,
// stride-40 LDS (2-way banks). es/ed moved to esed_kernel.
// =====================================================================
__global__ __launch_bounds__(256)
void fc_nodes_gemm(const bf16_t* __restrict__ hEnt, const bf16_t* __restrict__ hAtt,
                   const bf16_t* __restrict__ WfcB, const float* __restrict__ bfc,
                   bf16_t* __restrict__ nodes)
{
    constexpr int AST = 40;
    __shared__ __align__(16) bf16_t As[128 * AST];   // 10 KB
    __shared__ __align__(16) bf16_t Bs[128 * AST];   // 10 KB
    __shared__ const bf16_t* rowp[128];

    const int tid  = threadIdx.x;
    const int w    = tid >> 6;
    const int lane = tid & 63;
    const int wr = w >> 1, wc = w & 1;
    const int lr = lane & 15;
    const int lk = lane >> 4;
    const int m0 = blockIdx.x * 128, n0 = blockIdx.y * 128;

    if (tid < 128) {
        const int m = m0 + tid;
        const int g = m / NNODE, i = m - g * NNODE;
        rowp[tid] = (i == 0) ? (hEnt + (size_t)g * KPAD)
                             : (hAtt + (size_t)(g * 8 + (i - 1)) * KPAD);
    }
    __syncthreads();

    const int r0 = tid >> 2;
    const int cc = (tid & 3) * 8;
    const bf16_t* Arow0 = rowp[r0] + cc;
    const bf16_t* Arow1 = rowp[r0 + 64] + cc;
    const bf16_t* Brow0 = WfcB + (size_t)(n0 + r0) * KPAD + cc;
    const bf16_t* Brow1 = Brow0 + (size_t)64 * KPAD;

    f32x4_t acc[4][4];
#pragma unroll
    for (int i = 0; i < 4; ++i)
#pragma unroll
        for (int j = 0; j < 4; ++j) acc[i][j] = {0.f, 0.f, 0.f, 0.f};

    for (int k0 = 0; k0 < KPAD; k0 += 32) {
        const uint4 a0 = *(const uint4*)(Arow0 + k0);
        const uint4 a1 = *(const uint4*)(Arow1 + k0);
        const uint4 b0 = *(const uint4*)(Brow0 + k0);
        const uint4 b1 = *(const uint4*)(Brow1 + k0);
        __syncthreads();
        *(uint4*)&As[r0 * AST + cc]        = a0;
        *(uint4*)&As[(r0 + 64) * AST + cc] = a1;
        *(uint4*)&Bs[r0 * AST + cc]        = b0;
        *(uint4*)&Bs[(r0 + 64) * AST + cc] = b1;
        __syncthreads();

        bf16x8_t af[4], bfr[4];
#pragma unroll
        for (int i = 0; i < 4; ++i) {
            af[i]  = *(const bf16x8_t*)&As[(wr * 64 + i * 16 + lr) * AST + lk * 8];
            bfr[i] = *(const bf16x8_t*)&Bs[(wc * 64 + i * 16 + lr) * AST + lk * 8];
        }
#pragma unroll
        for (int mi = 0; mi < 4; ++mi)
#pragma unroll
            for (int ni = 0; ni < 4; ++ni)
                acc[mi][ni] = __builtin_amdgcn_mfma_f32_16x16x32_bf16(
                    af[mi], bfr[ni], acc[mi][ni], 0, 0, 0);
    }

#pragma unroll
    for (int mi = 0; mi < 4; ++mi) {
#pragma unroll
        for (int ni = 0; ni < 4; ++ni) {
            const int n = n0 + wc * 64 + ni * 16 + lr;
            const float bb = bfc[n];
#pragma unroll
            for (int r = 0; r < 4; ++r) {
                const int m = m0 + wr * 64 + mi * 16 + lk * 4 + r;
                float v = acc[mi][ni][r] + bb;
                v = v > 0.f ? v : 0.f;
                nodes[(size_t)m * HDIM + n] = f2bf(v);
            }
        }
    }
}

// es[m] = nodes[m] . asW ; ed[m] = nodes[m] . adW. One wave per row.
__global__ __launch_bounds__(256)
void esed_kernel(const bf16_t* __restrict__ nodes,
                 const float* __restrict__ asW, const float* __restrict__ adW,
                 float* __restrict__ es, float* __restrict__ ed)
{
    const int m    = (blockIdx.x * 256 + threadIdx.x) >> 6;   // row
    const int lane = threadIdx.x & 63;
    const bf16_t* row = nodes + (size_t)m * HDIM;

    const uint4 v0 = *(const uint4*)(row + lane * 8);
    const uint4 v1 = *(const uint4*)(row + 512 + lane * 8);

    float s = 0.f, d = 0.f;
    const unsigned int* w0 = (const unsigned int*)&v0;
    const unsigned int* w1 = (const unsigned int*)&v1;
#pragma unroll
    for (int e = 0; e < 4; ++e) {
        const int c0 = lane * 8 + 2 * e;
        const float x0 = bf2f((bf16_t)(w0[e] & 0xffff));
        const float x1 = bf2f((bf16_t)(w0[e] >> 16));
        s = fmaf(x0, asW[c0], s);     s = fmaf(x1, asW[c0 + 1], s);
        d = fmaf(x0, adW[c0], d);     d = fmaf(x1, adW[c0 + 1], d);
        const int c1 = 512 + lane * 8 + 2 * e;
        const float y0 = bf2f((bf16_t)(w1[e] & 0xffff));
        const float y1 = bf2f((bf16_t)(w1[e] >> 16));
        s = fmaf(y0, asW[c1], s);     s = fmaf(y1, asW[c1 + 1], s);
        d = fmaf(y0, adW[c1], d);     d = fmaf(y1, adW[c1 + 1], d);
    }
#pragma unroll
    for (int mask = 1; mask < 64; mask <<= 1) {
        s += __shfl_xor(s, mask, 64);
        d += __shfl_xor(d, mask, 64);
    }
    if (lane == 0) { es[m] = s; ed[m] = d; }
}

// =====================================================================
// Prep kernels
// =====================================================================
__global__ __launch_bounds__(256)
void convert_emb_kernel(const float* __restrict__ emb, bf16_t* __restrict__ embB)
{
    const int idx = blockIdx.x * 256 + threadIdx.x;    // over V_*40
    if (idx >= V_ * 40) return;
    const int row = idx / 40, c8 = (idx - row * 40) * 8;
    bf16_t o[8];
#pragma unroll
    for (int e = 0; e < 8; ++e) {
        const int c = c8 + e;
        o[e] = (c < WDIM) ? f2bf(emb[(size_t)row * WDIM + c]) : (bf16_t)0;
    }
    *(ushort4*)(embB + (size_t)row * KPAD + c8)     = *(ushort4*)&o[0];
    *(ushort4*)(embB + (size_t)row * KPAD + c8 + 4) = *(ushort4*)&o[4];
}

// W [3*300][300] fp32 -> dst[1024][320] bf16, INTERLEAVED rows n = 3*j + g
__global__ __launch_bounds__(256)
void build_w3i_kernel(const float* __restrict__ W, bf16_t* __restrict__ dst)
{
    const int idx = blockIdx.x * 256 + threadIdx.x;    // over 1024*320
    if (idx >= HDIM * KPAD) return;
    const int n = idx / KPAD, k = idx - n * KPAD;
    float v = 0.f;
    if (n < 960) {
        const int j = n / 3, g = n - j * 3;
        if (j < WDIM && k < WDIM)
            v = W[(size_t)(g * WDIM + j) * WDIM + k];
    }
    dst[idx] = f2bf(v);
}

__global__ __launch_bounds__(256)
void build_wfc_kernel(const float* __restrict__ Wfc, bf16_t* __restrict__ Wb)
{
    const int idx = blockIdx.x * 256 + threadIdx.x;    // over 1024*320
    if (idx >= HDIM * KPAD) return;
    const int n = idx / KPAD, k = idx - n * KPAD;
    Wb[idx] = f2bf(k < WDIM ? Wfc[(size_t)n * WDIM + k] : 0.f);
}

__global__ __launch_bounds__(256)
void build_wg_kernel(const float* __restrict__ Wg, bf16_t* __restrict__ Wb)
{
    const int idx = blockIdx.x * 256 + threadIdx.x;    // over 1024*1024
    Wb[idx] = f2bf(Wg[idx]);
}

// asW = a_src @ Wg, adW = a_dst @ Wg
__global__ __launch_bounds__(256)
void asw_kernel(const float* __restrict__ Wg,
                const float* __restrict__ a_src, const float* __restrict__ a_dst,
                float* __restrict__ asW, float* __restrict__ adW)
{
    const int k = blockIdx.x * 256 + threadIdx.x;
    float s = 0.f, d = 0.f;
    for (int n = 0; n < HDIM; ++n) {
        const float w = Wg[(size_t)n * HDIM + k];
        s = fmaf(a_src[n], w, s);
        d = fmaf(a_dst[n], w, d);
    }
    asW[k] = s; adW[k] = d;
}

// Row-0 star attention -> mixed[g] = sum_j alpha_j * nodes[g*9+j] (bf16)
__global__ __launch_bounds__(256)
void attn_mix_kernel(const bf16_t* __restrict__ nodes,
                     const float* __restrict__ es, const float* __restrict__ ed,
                     bf16_t* __restrict__ mixed)
{
    const int g = blockIdx.x;
    const float e0 = es[(size_t)g * NNODE];
    const float* edg = ed + (size_t)g * NNODE;

    float w[NNODE], mx = -1e30f;
#pragma unroll
    for (int j = 0; j < NNODE; ++j) {
        float v = e0 + edg[j];
        v = v >= 0.f ? v : 0.2f * v;
        w[j] = v; mx = fmaxf(mx, v);
    }
    float denom = 0.f;
#pragma unroll
    for (int j = 0; j < NNODE; ++j) { w[j] = expf(w[j] - mx); denom += w[j]; }
    const float inv = 1.f / denom;

    const int c = threadIdx.x * 4;
    float4 acc = {0.f, 0.f, 0.f, 0.f};
#pragma unroll
    for (int j = 0; j < NNODE; ++j) {
        const float a = w[j] * inv;
        const ushort4 h4 = *(const ushort4*)(nodes + (size_t)(g * NNODE + j) * HDIM + c);
        acc.x = fmaf(a, bf2f(h4.x), acc.x);
        acc.y = fmaf(a, bf2f(h4.y), acc.y);
        acc.z = fmaf(a, bf2f(h4.z), acc.z);
        acc.w = fmaf(a, bf2f(h4.w), acc.w);
    }
    ushort4 o;
    o.x = f2bf(acc.x); o.y = f2bf(acc.y); o.z = f2bf(acc.z); o.w = f2bf(acc.w);
    *(ushort4*)(mixed + (size_t)g * HDIM + c) = o;
}

// -------- workspace layout (~134 MiB; 157 MiB known-safe) --------
constexpr size_t SZ_EMBB  = (size_t)VP * KPAD * sizeof(bf16_t);      // 19.58 MB
constexpr size_t SZ_PROJ  = (size_t)VP * PROJW * sizeof(bf16_t);     // 62.65 MB
constexpr size_t SZ_HATT  = (size_t)GA * KPAD * sizeof(bf16_t);      // 20.97 MB x2
constexpr size_t SZ_HENT  = (size_t)G * KPAD * sizeof(bf16_t);       //  2.62 MB x2
constexpr size_t SZ_WIH3  = (size_t)HDIM * KPAD * sizeof(bf16_t);
constexpr size_t SZ_WHH3E = (size_t)HDIM * KPAD * sizeof(bf16_t);    //  0.66 MB x2 (1024 rows)
constexpr size_t SZ_WFC   = (size_t)HDIM * KPAD * sizeof(bf16_t);
constexpr size_t SZ_WG    = (size_t)HDIM * HDIM * sizeof(bf16_t);
constexpr size_t SZ_AW    = (size_t)HDIM * sizeof(float);
constexpr size_t SZ_VEC   = (size_t)MROWS * sizeof(float);
constexpr size_t SZ_NODE  = (size_t)MROWS * HDIM * sizeof(bf16_t);   // 75.5 MB
constexpr size_t SZ_MIX   = (size_t)G * HDIM * sizeof(bf16_t);
constexpr size_t WS_NEED  = SZ_EMBB + SZ_PROJ + 2 * SZ_HATT + 2 * SZ_HENT +
                            SZ_WIH3 + 2 * SZ_WHH3E + SZ_WFC + SZ_WG +
                            2 * SZ_AW + 2 * SZ_VEC;
static_assert(SZ_NODE <= SZ_EMBB + SZ_PROJ, "nodes overlays embB+proj");
static_assert(SZ_MIX  <= 2 * SZ_HATT,       "mixed overlays hAtt pair");

} // namespace

extern "C" void kernel_launch(void* const* d_in, const int* in_sizes, int n_in,
                              void* d_out, int out_size, void* d_ws, size_t ws_size,
                              hipStream_t stream)
{
    (void)in_sizes; (void)n_in; (void)out_size;
    if (ws_size < WS_NEED) return;   // clean absmax failure instead of fault

    const int*   ent_tok  = (const int*)  d_in[0];
    const int*   ent_len  = (const int*)  d_in[1];
    const int*   at_tok   = (const int*)  d_in[3];
    const int*   at_len   = (const int*)  d_in[4];
    const float* emb      = (const float*)d_in[6];
    const float* Wih_ent  = (const float*)d_in[7];
    const float* Whh_ent  = (const float*)d_in[8];
    const float* bih_ent  = (const float*)d_in[9];
    const float* bhh_ent  = (const float*)d_in[10];
    const float* Wih_attr = (const float*)d_in[11];
    const float* Whh_attr = (const float*)d_in[12];
    const float* bih_attr = (const float*)d_in[13];
    const float* bhh_attr = (const float*)d_in[14];
    const float* Wfc      = (const float*)d_in[15];
    const float* bfc      = (const float*)d_in[16];
    const float* Wg       = (const float*)d_in[17];
    const float* a_src    = (const float*)d_in[18];
    const float* a_dst    = (const float*)d_in[19];
    float* out = (float*)d_out;

    char* p = (char*)d_ws;
    bf16_t* embB  = (bf16_t*)p; p += SZ_EMBB;
    bf16_t* proj  = (bf16_t*)p; p += SZ_PROJ;
    bf16_t* hAtt[2];
    hAtt[0] = (bf16_t*)p; p += SZ_HATT;
    hAtt[1] = (bf16_t*)p; p += SZ_HATT;
    bf16_t* hEnt   = (bf16_t*)p; p += SZ_HENT;
    bf16_t* hEnt2  = (bf16_t*)p; p += SZ_HENT;
    bf16_t* Wih3   = (bf16_t*)p; p += SZ_WIH3;
    bf16_t* Whh3_a = (bf16_t*)p; p += SZ_WHH3E;
    bf16_t* Whh3_e = (bf16_t*)p; p += SZ_WHH3E;
    bf16_t* WfcB   = (bf16_t*)p; p += SZ_WFC;
    bf16_t* WgB    = (bf16_t*)p; p += SZ_WG;
    float*  asW    = (float*)p;  p += SZ_AW;
    float*  adW    = (float*)p;  p += SZ_AW;
    float*  es     = (float*)p;  p += SZ_VEC;
    float*  ed     = (float*)p;  p += SZ_VEC;
    bf16_t* nodes  = embB;       // overlay: embB+proj dead after GRU loops
    bf16_t* mixed  = hAtt[0];    // overlay: hAtt dead after fc_nodes_gemm

    // zero h ping-pong buffers (h0 = 0; pad cols must stay 0)
    hipMemsetAsync(hAtt[0], 0, SZ_HATT, stream);
    hipMemsetAsync(hAtt[1], 0, SZ_HATT, stream);
    hipMemsetAsync(hEnt,  0, SZ_HENT, stream);
    hipMemsetAsync(hEnt2, 0, SZ_HENT, stream);

    // prep (both GRUs use the INTERLEAVED n=3j+g layout)
    convert_emb_kernel<<<dim3((V_ * 40 + 255) / 256), 256, 0, stream>>>(emb, embB);
    build_w3i_kernel<<<dim3(HDIM * KPAD / 256), 256, 0, stream>>>(Wih_attr, Wih3);
    build_w3i_kernel<<<dim3(HDIM * KPAD / 256), 256, 0, stream>>>(Whh_attr, Whh3_a);
    build_w3i_kernel<<<dim3(HDIM * KPAD / 256), 256, 0, stream>>>(Whh_ent, Whh3_e);
    build_wfc_kernel<<<dim3(HDIM * KPAD / 256), 256, 0, stream>>>(Wfc, WfcB);
    build_wg_kernel<<<dim3(HDIM * HDIM / 256), 256, 0, stream>>>(Wg, WgB);
    asw_kernel<<<dim3(HDIM / 256), 256, 0, stream>>>(Wg, a_src, a_dst, asW, adW);

    // attr vocab projection (interleaved): proj[v] = embB[v] @ Wih3i_attr^T
    mfma_gemm<0><<<dim3(VP / 128, PROJW / 128), 256, 0, stream>>>(
        embB, Wih3, proj, KPAD, KPAD, PROJW, KPAD);

    // attr GRU: T=4 fused GEMM+epilogue steps, grid 256x8 = 2048 blocks
    for (int t = 0; t < TA_; ++t)
        gru_step_fused<<<dim3(GA / 128, 8), 512, 0, stream>>>(
            hAtt[t & 1], hAtt[(t + 1) & 1], Whh3_a, proj, at_tok, at_len,
            bih_attr, bhh_attr, TA_, t);

    // ent vocab projection (interleaved); overwrite proj
    build_w3i_kernel<<<dim3(HDIM * KPAD / 256), 256, 0, stream>>>(Wih_ent, Wih3);
    mfma_gemm<0><<<dim3(VP / 128, PROJW / 128), 256, 0, stream>>>(
        embB, Wih3, proj, KPAD, KPAD, PROJW, KPAD);

    // ent GRU: 8 fused GEMM+epilogue step launches, ping-pong h
    bf16_t* hb[2] = { hEnt, hEnt2 };
    for (int t = 0; t < TE_; ++t)
        gru_step_fused<<<dim3(G / 128, 8), 512, 0, stream>>>(
            hb[t & 1], hb[(t + 1) & 1], Whh3_e, proj, ent_tok, ent_len,
            bih_ent, bhh_ent, TE_, t);

    // nodes = relu(h @ Wfc^T + bfc) — proper GEMM with gathered A rows
    fc_nodes_gemm<<<dim3(MROWS / 128, HDIM / 128), 256, 0, stream>>>(
        hEnt, hAtt[0], WfcB, bfc, nodes);

    // es/ed = nodes . asW/adW (one wave per row)
    esed_kernel<<<dim3(MROWS / 4), 256, 0, stream>>>(nodes, asW, adW, es, ed);

    // row-0 softmax + node mixing
    attn_mix_kernel<<<dim3(G), 256, 0, stream>>>(nodes, es, ed, mixed);

    // out = elu(mixed @ Wg^T)
    mfma_gemm<2><<<dim3(G / 128, HDIM / 128), 256, 0, stream>>>(
        mixed, WgB, out, HDIM, HDIM, HDIM, HDIM);
}

// Round 8
// 763.545 us; speedup vs baseline: 1.3986x; 1.0055x over previous
//
#include <hip/hip_runtime.h>
#include <math.h>

namespace {

typedef unsigned short bf16_t;
typedef __bf16  bf16x8_t __attribute__((ext_vector_type(8)));
typedef float   f32x4_t  __attribute__((ext_vector_type(4)));
typedef unsigned int u32x4 __attribute__((ext_vector_type(4)));

constexpr int G     = 4096;      // BS*E
constexpr int GA    = 32768;     // G*A
constexpr int WDIM  = 300;
constexpr int KPAD  = 320;
constexpr int HDIM  = 1024;
constexpr int NNODE = 9;
constexpr int MROWS = G * NNODE; // 36864
constexpr int TE_   = 8;
constexpr int TA_   = 4;
constexpr int V_    = 30522;
constexpr int VP    = 30592;     // 239*128
constexpr int PROJW = 1024;

__device__ __forceinline__ float bf2f(bf16_t b) {
    union { unsigned int u; float f; } v; v.u = ((unsigned int)b) << 16; return v.f;
}
__device__ __forceinline__ bf16_t f2bf(float f) {
    union { float f; unsigned int u; } v; v.f = f;
    unsigned int r = v.u + 0x7FFFu + ((v.u >> 16) & 1u);   // RNE
    return (bf16_t)(r >> 16);
}

// =====================================================================
// Generic 128x128-tile bf16 MFMA GEMM: C = A[M,K] @ B[N,K]^T
// MODE 0: C bf16 (vocab projection)   MODE 2: C fp32 with elu (final out)
// R16: LDS row stride 40 bf16 (conflict-free starts for ds_read_b128).
// =====================================================================
template<int MODE>
__global__ __launch_bounds__(256)
void mfma_gemm(const bf16_t* __restrict__ A, const bf16_t* __restrict__ B,
               void* __restrict__ Cv, int lda, int ldb, int ldc, int K)
{
    constexpr int AST = 40;                  // padded LDS row stride (bf16)
    __shared__ __align__(16) bf16_t As[128 * AST];   // 10 KB
    __shared__ __align__(16) bf16_t Bs[128 * AST];   // 10 KB

    const int tid  = threadIdx.x;
    const int w    = tid >> 6;
    const int lane = tid & 63;
    const int wr = w >> 1, wc = w & 1;
    const int lr = lane & 15;
    const int lk = lane >> 4;
    const int m0 = blockIdx.x * 128, n0 = blockIdx.y * 128;

    const int r0 = tid >> 2;
    const int cc = (tid & 3) * 8;
    const bf16_t* Arow0 = A + (size_t)(m0 + r0) * lda + cc;
    const bf16_t* Arow1 = Arow0 + (size_t)64 * lda;
    const bf16_t* Brow0 = B + (size_t)(n0 + r0) * ldb + cc;
    const bf16_t* Brow1 = Brow0 + (size_t)64 * ldb;

    f32x4_t acc[4][4];
#pragma unroll
    for (int i = 0; i < 4; ++i)
#pragma unroll
        for (int j = 0; j < 4; ++j) acc[i][j] = {0.f, 0.f, 0.f, 0.f};

    for (int k0 = 0; k0 < K; k0 += 32) {
        const uint4 a0 = *(const uint4*)(Arow0 + k0);
        const uint4 a1 = *(const uint4*)(Arow1 + k0);
        const uint4 b0 = *(const uint4*)(Brow0 + k0);
        const uint4 b1 = *(const uint4*)(Brow1 + k0);
        __syncthreads();
        *(uint4*)&As[r0 * AST + cc]        = a0;
        *(uint4*)&As[(r0 + 64) * AST + cc] = a1;
        *(uint4*)&Bs[r0 * AST + cc]        = b0;
        *(uint4*)&Bs[(r0 + 64) * AST + cc] = b1;
        __syncthreads();

        bf16x8_t af[4], bfr[4];
#pragma unroll
        for (int i = 0; i < 4; ++i) {
            af[i]  = *(const bf16x8_t*)&As[(wr * 64 + i * 16 + lr) * AST + lk * 8];
            bfr[i] = *(const bf16x8_t*)&Bs[(wc * 64 + i * 16 + lr) * AST + lk * 8];
        }
#pragma unroll
        for (int mi = 0; mi < 4; ++mi)
#pragma unroll
            for (int ni = 0; ni < 4; ++ni)
                acc[mi][ni] = __builtin_amdgcn_mfma_f32_16x16x32_bf16(
                    af[mi], bfr[ni], acc[mi][ni], 0, 0, 0);
    }

#pragma unroll
    for (int mi = 0; mi < 4; ++mi) {
#pragma unroll
        for (int ni = 0; ni < 4; ++ni) {
            const int n = n0 + wc * 64 + ni * 16 + lr;
#pragma unroll
            for (int r = 0; r < 4; ++r) {
                const int m = m0 + wr * 64 + mi * 16 + lk * 4 + r;
                const float v = acc[mi][ni][r];
                if (MODE == 0)
                    ((bf16_t*)Cv)[(size_t)m * ldc + n] = f2bf(v);
                else
                    ((float*)Cv)[(size_t)m * ldc + n] = v > 0.f ? v : expm1f(v);
            }
        }
    }
}

// =====================================================================
// GRU step (used for BOTH ent and attr). One launch per step; fused
// GEMM + gate epilogue. gates[M x 960] = h @ Whh3i^T, tile 128x120
// (interleaved n=3j+g), grid (M/128, 8), 512 thr. Scatter col<120 (R12).
// R17: (a) T2 XOR-swizzle on the As/Bs 16-B slot (slot ^= row&3) both
// write+read: kills the 4-way ds_read_b128 bank conflict of the stride-32
// layout at zero LDS cost (padding would break 2-block residency or 16-B
// alignment). (b) T14 prefetch: tok/len/xp/h epilogue loads ISSUE before
// the k-loop so their ~900cyc gather latency hides under the 10 GEMM
// iters; early-return replaced by store predicate (loads all in-bounds).
// =====================================================================
__global__ __launch_bounds__(512)
void gru_step_fused(const bf16_t* __restrict__ hin,     // [M][KPAD]
                    bf16_t* __restrict__ hout,          // [M][KPAD]
                    const bf16_t* __restrict__ Whh3i,   // [1024][320] n=3j+g
                    const bf16_t* __restrict__ proj,    // [VP][1024]  n=3j+g
                    const int* __restrict__ tokens,
                    const int* __restrict__ lengths,
                    const float* __restrict__ bih, const float* __restrict__ bhh,
                    int T, int t)
{
    constexpr int GSTRF = 123;               // odd f32 stride; 120 used cols
    __shared__ __align__(16) bf16_t As[128 * 32];   // 8 KB
    __shared__ __align__(16) bf16_t Bs[128 * 32];   // 8 KB
    __shared__ float gsm[128 * GSTRF];              // 61.5 KB

    const int tid = threadIdx.x;
    const int w = tid >> 6, lane = tid & 63;
    const int lr = lane & 15, lk = lane >> 4;
    const int wr = w >> 2, wc = w & 3;       // 2 (M) x 4 (N) waves
    const int m0 = blockIdx.x * 128;
    const int nb = blockIdx.y;               // 0..7
    const int n0 = nb * 120;

    // ---- T14 prefetch: issue epilogue loads BEFORE the GEMM ----
    const int ml = tid >> 2, q = tid & 3;
    const int m  = m0 + ml;
    const int jb = nb * 40 + q * 10;
    const bool estore = !(nb == 7 && q >= 2);   // j >= 300 never stored
    int len = lengths[m]; if (len < 1) len = 1;
    const bool act = (t < len);
    const int tok = tokens[(size_t)m * T + t];

    const unsigned int* xpp =
        (const unsigned int*)(proj + (size_t)tok * PROJW + n0 + q * 30);
    unsigned int xw[15];
#pragma unroll
    for (int i = 0; i < 15; ++i) xw[i] = xpp[i];

    const unsigned int* hop = (const unsigned int*)(hin + (size_t)m * KPAD + jb);
    unsigned int hw[5];
#pragma unroll
    for (int i = 0; i < 5; ++i) hw[i] = hop[i];

    // ---- GEMM ----
    const int sr = tid >> 2, sq = tid & 3;   // staging row / 16B-slot
    const bf16_t* Ap = hin   + (size_t)(m0 + sr) * KPAD + sq * 8;
    const bf16_t* Bp = Whh3i + (size_t)(n0 + sr) * KPAD + sq * 8;
    const int ssl = (sq ^ (sr & 3)) * 8;     // swizzled staging slot

    f32x4_t acc[4][2];
#pragma unroll
    for (int mi = 0; mi < 4; ++mi)
#pragma unroll
        for (int ni = 0; ni < 2; ++ni) acc[mi][ni] = {0.f, 0.f, 0.f, 0.f};

    for (int k0 = 0; k0 < KPAD; k0 += 32) {
        const uint4 av = *(const uint4*)(Ap + k0);
        const uint4 bv = *(const uint4*)(Bp + k0);
        __syncthreads();
        *(uint4*)&As[sr * 32 + ssl] = av;
        *(uint4*)&Bs[sr * 32 + ssl] = bv;
        __syncthreads();

        // read slot swizzle: row&3 == lr&3 (row bases are multiples of 4)
        const int asl = (lk ^ (lr & 3)) * 8;
        bf16x8_t af[4], bfr[2];
#pragma unroll
        for (int mi = 0; mi < 4; ++mi)
            af[mi] = *(const bf16x8_t*)&As[(wr * 64 + mi * 16 + lr) * 32 + asl];
#pragma unroll
        for (int ni = 0; ni < 2; ++ni)
            bfr[ni] = *(const bf16x8_t*)&Bs[(wc * 32 + ni * 16 + lr) * 32 + asl];
#pragma unroll
        for (int mi = 0; mi < 4; ++mi)
#pragma unroll
            for (int ni = 0; ni < 2; ++ni)
                acc[mi][ni] = __builtin_amdgcn_mfma_f32_16x16x32_bf16(
                    af[mi], bfr[ni], acc[mi][ni], 0, 0, 0);
    }

    // scatter wave tiles to gates LDS (row = M, col = N); cols >= 120 are
    // the B-stage overlap belonging to the next nb block — DO NOT scatter
#pragma unroll
    for (int ni = 0; ni < 2; ++ni) {
        const int col = wc * 32 + ni * 16 + lr;
        if (col < 120) {
#pragma unroll
            for (int mi = 0; mi < 4; ++mi)
#pragma unroll
                for (int r = 0; r < 4; ++r)
                    gsm[(wr * 64 + mi * 16 + lk * 4 + r) * GSTRF + col]
                        = acc[mi][ni][r];
        }
    }
    __syncthreads();

    // ---- fused GRU epilogue (operands prefetched above) ----
    unsigned int ow[5];
#pragma unroll
    for (int u = 0; u < 10; ++u) {
        const int j = jb + u;
        const bf16_t hob = (bf16_t)((u & 1) ? (hw[u >> 1] >> 16) : (hw[u >> 1] & 0xffff));
        const float hold = bf2f(hob);
        float hv = hold;
        if (act) {
            const int e0 = 3 * u;
            const float xr = bf2f((bf16_t)((e0 & 1)       ? (xw[e0 >> 1] >> 16)       : (xw[e0 >> 1] & 0xffff)));
            const float xz = bf2f((bf16_t)(((e0 + 1) & 1) ? (xw[(e0 + 1) >> 1] >> 16) : (xw[(e0 + 1) >> 1] & 0xffff)));
            const float xn = bf2f((bf16_t)(((e0 + 2) & 1) ? (xw[(e0 + 2) >> 1] >> 16) : (xw[(e0 + 2) >> 1] & 0xffff)));
            const int nl = q * 30 + 3 * u;
            const float g0 = gsm[ml * GSTRF + nl];
            const float g1 = gsm[ml * GSTRF + nl + 1];
            const float g2 = gsm[ml * GSTRF + nl + 2];
            const float rr = 1.f / (1.f + expf(-(g0 + xr + bih[j] + bhh[j])));
            const float zz = 1.f / (1.f + expf(-(g1 + xz + bih[WDIM + j] + bhh[WDIM + j])));
            const float nn = tanhf(xn + bih[2 * WDIM + j] + rr * (g2 + bhh[2 * WDIM + j]));
            hv = (1.f - zz) * nn + zz * hold;
        }
        const bf16_t hb_ = f2bf(hv);
        if ((u & 1) == 0) ow[u >> 1] = hb_;
        else              ow[u >> 1] |= ((unsigned int)hb_) << 16;
    }
    if (estore) {
        unsigned int* outp = (unsigned int*)(hout + (size_t)m * KPAD + jb);
#pragma unroll
        for (int i = 0; i < 5; ++i) outp[i] = ow[i];
    }
}

// =====================================================================
// R16: nodes = relu(h @ Wfc^T + bfc) as a PROPER 128x128 GEMM with a
// gathered A (128-entry LDS pointer table). Stride-40 LDS.
// =====================================================================
__global__ __launch_bounds__(256)
void fc_nodes_gemm(const bf16_t* __restrict__ hEnt, const bf16_t* __restrict__ hAtt,
                   const bf16_t* __restrict__ WfcB, const float* __restrict__ bfc,
                   bf16_t* __restrict__ nodes)
{
    constexpr int AST = 40;
    __shared__ __align__(16) bf16_t As[128 * AST];   // 10 KB
    __shared__ __align__(16) bf16_t Bs[128 * AST];   // 10 KB
    __shared__ const bf16_t* rowp[128];

    const int tid  = threadIdx.x;
    const int w    = tid >> 6;
    const int lane = tid & 63;
    const int wr = w >> 1, wc = w & 1;
    const int lr = lane & 15;
    const int lk = lane >> 4;
    const int m0 = blockIdx.x * 128, n0 = blockIdx.y * 128;

    if (tid < 128) {
        const int m = m0 + tid;
        const int g = m / NNODE, i = m - g * NNODE;
        rowp[tid] = (i == 0) ? (hEnt + (size_t)g * KPAD)
                             : (hAtt + (size_t)(g * 8 + (i - 1)) * KPAD);
    }
    __syncthreads();

    const int r0 = tid >> 2;
    const int cc = (tid & 3) * 8;
    const bf16_t* Arow0 = rowp[r0] + cc;
    const bf16_t* Arow1 = rowp[r0 + 64] + cc;
    const bf16_t* Brow0 = WfcB + (size_t)(n0 + r0) * KPAD + cc;
    const bf16_t* Brow1 = Brow0 + (size_t)64 * KPAD;

    f32x4_t acc[4][4];
#pragma unroll
    for (int i = 0; i < 4; ++i)
#pragma unroll
        for (int j = 0; j < 4; ++j) acc[i][j] = {0.f, 0.f, 0.f, 0.f};

    for (int k0 = 0; k0 < KPAD; k0 += 32) {
        const uint4 a0 = *(const uint4*)(Arow0 + k0);
        const uint4 a1 = *(const uint4*)(Arow1 + k0);
        const uint4 b0 = *(const uint4*)(Brow0 + k0);
        const uint4 b1 = *(const uint4*)(Brow1 + k0);
        __syncthreads();
        *(uint4*)&As[r0 * AST + cc]        = a0;
        *(uint4*)&As[(r0 + 64) * AST + cc] = a1;
        *(uint4*)&Bs[r0 * AST + cc]        = b0;
        *(uint4*)&Bs[(r0 + 64) * AST + cc] = b1;
        __syncthreads();

        bf16x8_t af[4], bfr[4];
#pragma unroll
        for (int i = 0; i < 4; ++i) {
            af[i]  = *(const bf16x8_t*)&As[(wr * 64 + i * 16 + lr) * AST + lk * 8];
            bfr[i] = *(const bf16x8_t*)&Bs[(wc * 64 + i * 16 + lr) * AST + lk * 8];
        }
#pragma unroll
        for (int mi = 0; mi < 4; ++mi)
#pragma unroll
            for (int ni = 0; ni < 4; ++ni)
                acc[mi][ni] = __builtin_amdgcn_mfma_f32_16x16x32_bf16(
                    af[mi], bfr[ni], acc[mi][ni], 0, 0, 0);
    }

#pragma unroll
    for (int mi = 0; mi < 4; ++mi) {
#pragma unroll
        for (int ni = 0; ni < 4; ++ni) {
            const int n = n0 + wc * 64 + ni * 16 + lr;
            const float bb = bfc[n];
#pragma unroll
            for (int r = 0; r < 4; ++r) {
                const int m = m0 + wr * 64 + mi * 16 + lk * 4 + r;
                float v = acc[mi][ni][r] + bb;
                v = v > 0.f ? v : 0.f;
                nodes[(size_t)m * HDIM + n] = f2bf(v);
            }
        }
    }
}

// es[m] = nodes[m] . asW ; ed[m] = nodes[m] . adW. One wave per row.
__global__ __launch_bounds__(256)
void esed_kernel(const bf16_t* __restrict__ nodes,
                 const float* __restrict__ asW, const float* __restrict__ adW,
                 float* __restrict__ es, float* __restrict__ ed)
{
    const int m    = (blockIdx.x * 256 + threadIdx.x) >> 6;   // row
    const int lane = threadIdx.x & 63;
    const bf16_t* row = nodes + (size_t)m * HDIM;

    const uint4 v0 = *(const uint4*)(row + lane * 8);
    const uint4 v1 = *(const uint4*)(row + 512 + lane * 8);

    float s = 0.f, d = 0.f;
    const unsigned int* w0 = (const unsigned int*)&v0;
    const unsigned int* w1 = (const unsigned int*)&v1;
#pragma unroll
    for (int e = 0; e < 4; ++e) {
        const int c0 = lane * 8 + 2 * e;
        const float x0 = bf2f((bf16_t)(w0[e] & 0xffff));
        const float x1 = bf2f((bf16_t)(w0[e] >> 16));
        s = fmaf(x0, asW[c0], s);     s = fmaf(x1, asW[c0 + 1], s);
        d = fmaf(x0, adW[c0], d);     d = fmaf(x1, adW[c0 + 1], d);
        const int c1 = 512 + lane * 8 + 2 * e;
        const float y0 = bf2f((bf16_t)(w1[e] & 0xffff));
        const float y1 = bf2f((bf16_t)(w1[e] >> 16));
        s = fmaf(y0, asW[c1], s);     s = fmaf(y1, asW[c1 + 1], s);
        d = fmaf(y0, adW[c1], d);     d = fmaf(y1, adW[c1 + 1], d);
    }
#pragma unroll
    for (int mask = 1; mask < 64; mask <<= 1) {
        s += __shfl_xor(s, mask, 64);
        d += __shfl_xor(d, mask, 64);
    }
    if (lane == 0) { es[m] = s; ed[m] = d; }
}

// =====================================================================
// Prep kernels
// =====================================================================
__global__ __launch_bounds__(256)
void convert_emb_kernel(const float* __restrict__ emb, bf16_t* __restrict__ embB)
{
    const int idx = blockIdx.x * 256 + threadIdx.x;    // over V_*40
    if (idx >= V_ * 40) return;
    const int row = idx / 40, c8 = (idx - row * 40) * 8;
    bf16_t o[8];
#pragma unroll
    for (int e = 0; e < 8; ++e) {
        const int c = c8 + e;
        o[e] = (c < WDIM) ? f2bf(emb[(size_t)row * WDIM + c]) : (bf16_t)0;
    }
    *(ushort4*)(embB + (size_t)row * KPAD + c8)     = *(ushort4*)&o[0];
    *(ushort4*)(embB + (size_t)row * KPAD + c8 + 4) = *(ushort4*)&o[4];
}

// W [3*300][300] fp32 -> dst[1024][320] bf16, INTERLEAVED rows n = 3*j + g
__global__ __launch_bounds__(256)
void build_w3i_kernel(const float* __restrict__ W, bf16_t* __restrict__ dst)
{
    const int idx = blockIdx.x * 256 + threadIdx.x;    // over 1024*320
    if (idx >= HDIM * KPAD) return;
    const int n = idx / KPAD, k = idx - n * KPAD;
    float v = 0.f;
    if (n < 960) {
        const int j = n / 3, g = n - j * 3;
        if (j < WDIM && k < WDIM)
            v = W[(size_t)(g * WDIM + j) * WDIM + k];
    }
    dst[idx] = f2bf(v);
}

__global__ __launch_bounds__(256)
void build_wfc_kernel(const float* __restrict__ Wfc, bf16_t* __restrict__ Wb)
{
    const int idx = blockIdx.x * 256 + threadIdx.x;    // over 1024*320
    if (idx >= HDIM * KPAD) return;
    const int n = idx / KPAD, k = idx - n * KPAD;
    Wb[idx] = f2bf(k < WDIM ? Wfc[(size_t)n * WDIM + k] : 0.f);
}

__global__ __launch_bounds__(256)
void build_wg_kernel(const float* __restrict__ Wg, bf16_t* __restrict__ Wb)
{
    const int idx = blockIdx.x * 256 + threadIdx.x;    // over 1024*1024
    Wb[idx] = f2bf(Wg[idx]);
}

// asW = a_src @ Wg, adW = a_dst @ Wg
__global__ __launch_bounds__(256)
void asw_kernel(const float* __restrict__ Wg,
                const float* __restrict__ a_src, const float* __restrict__ a_dst,
                float* __restrict__ asW, float* __restrict__ adW)
{
    const int k = blockIdx.x * 256 + threadIdx.x;
    float s = 0.f, d = 0.f;
    for (int n = 0; n < HDIM; ++n) {
        const float w = Wg[(size_t)n * HDIM + k];
        s = fmaf(a_src[n], w, s);
        d = fmaf(a_dst[n], w, d);
    }
    asW[k] = s; adW[k] = d;
}

// Row-0 star attention -> mixed[g] = sum_j alpha_j * nodes[g*9+j] (bf16)
__global__ __launch_bounds__(256)
void attn_mix_kernel(const bf16_t* __restrict__ nodes,
                     const float* __restrict__ es, const float* __restrict__ ed,
                     bf16_t* __restrict__ mixed)
{
    const int g = blockIdx.x;
    const float e0 = es[(size_t)g * NNODE];
    const float* edg = ed + (size_t)g * NNODE;

    float w[NNODE], mx = -1e30f;
#pragma unroll
    for (int j = 0; j < NNODE; ++j) {
        float v = e0 + edg[j];
        v = v >= 0.f ? v : 0.2f * v;
        w[j] = v; mx = fmaxf(mx, v);
    }
    float denom = 0.f;
#pragma unroll
    for (int j = 0; j < NNODE; ++j) { w[j] = expf(w[j] - mx); denom += w[j]; }
    const float inv = 1.f / denom;

    const int c = threadIdx.x * 4;
    float4 acc = {0.f, 0.f, 0.f, 0.f};
#pragma unroll
    for (int j = 0; j < NNODE; ++j) {
        const float a = w[j] * inv;
        const ushort4 h4 = *(const ushort4*)(nodes + (size_t)(g * NNODE + j) * HDIM + c);
        acc.x = fmaf(a, bf2f(h4.x), acc.x);
        acc.y = fmaf(a, bf2f(h4.y), acc.y);
        acc.z = fmaf(a, bf2f(h4.z), acc.z);
        acc.w = fmaf(a, bf2f(h4.w), acc.w);
    }
    ushort4 o;
    o.x = f2bf(acc.x); o.y = f2bf(acc.y); o.z = f2bf(acc.z); o.w = f2bf(acc.w);
    *(ushort4*)(mixed + (size_t)g * HDIM + c) = o;
}

// -------- workspace layout (~134 MiB; 157 MiB known-safe) --------
constexpr size_t SZ_EMBB  = (size_t)VP * KPAD * sizeof(bf16_t);      // 19.58 MB
constexpr size_t SZ_PROJ  = (size_t)VP * PROJW * sizeof(bf16_t);     // 62.65 MB
constexpr size_t SZ_HATT  = (size_t)GA * KPAD * sizeof(bf16_t);      // 20.97 MB x2
constexpr size_t SZ_HENT  = (size_t)G * KPAD * sizeof(bf16_t);       //  2.62 MB x2
constexpr size_t SZ_WIH3  = (size_t)HDIM * KPAD * sizeof(bf16_t);
constexpr size_t SZ_WHH3E = (size_t)HDIM * KPAD * sizeof(bf16_t);    //  0.66 MB x2 (1024 rows)
constexpr size_t SZ_WFC   = (size_t)HDIM * KPAD * sizeof(bf16_t);
constexpr size_t SZ_WG    = (size_t)HDIM * HDIM * sizeof(bf16_t);
constexpr size_t SZ_AW    = (size_t)HDIM * sizeof(float);
constexpr size_t SZ_VEC   = (size_t)MROWS * sizeof(float);
constexpr size_t SZ_NODE  = (size_t)MROWS * HDIM * sizeof(bf16_t);   // 75.5 MB
constexpr size_t SZ_MIX   = (size_t)G * HDIM * sizeof(bf16_t);
constexpr size_t WS_NEED  = SZ_EMBB + SZ_PROJ + 2 * SZ_HATT + 2 * SZ_HENT +
                            SZ_WIH3 + 2 * SZ_WHH3E + SZ_WFC + SZ_WG +
                            2 * SZ_AW + 2 * SZ_VEC;
static_assert(SZ_NODE <= SZ_EMBB + SZ_PROJ, "nodes overlays embB+proj");
static_assert(SZ_MIX  <= 2 * SZ_HATT,       "mixed overlays hAtt pair");

} // namespace

extern "C" void kernel_launch(void* const* d_in, const int* in_sizes, int n_in,
                              void* d_out, int out_size, void* d_ws, size_t ws_size,
                              hipStream_t stream)
{
    (void)in_sizes; (void)n_in; (void)out_size;
    if (ws_size < WS_NEED) return;   // clean absmax failure instead of fault

    const int*   ent_tok  = (const int*)  d_in[0];
    const int*   ent_len  = (const int*)  d_in[1];
    const int*   at_tok   = (const int*)  d_in[3];
    const int*   at_len   = (const int*)  d_in[4];
    const float* emb      = (const float*)d_in[6];
    const float* Wih_ent  = (const float*)d_in[7];
    const float* Whh_ent  = (const float*)d_in[8];
    const float* bih_ent  = (const float*)d_in[9];
    const float* bhh_ent  = (const float*)d_in[10];
    const float* Wih_attr = (const float*)d_in[11];
    const float* Whh_attr = (const float*)d_in[12];
    const float* bih_attr = (const float*)d_in[13];
    const float* bhh_attr = (const float*)d_in[14];
    const float* Wfc      = (const float*)d_in[15];
    const float* bfc      = (const float*)d_in[16];
    const float* Wg       = (const float*)d_in[17];
    const float* a_src    = (const float*)d_in[18];
    const float* a_dst    = (const float*)d_in[19];
    float* out = (float*)d_out;

    char* p = (char*)d_ws;
    bf16_t* embB  = (bf16_t*)p; p += SZ_EMBB;
    bf16_t* proj  = (bf16_t*)p; p += SZ_PROJ;
    bf16_t* hAtt[2];
    hAtt[0] = (bf16_t*)p; p += SZ_HATT;
    hAtt[1] = (bf16_t*)p; p += SZ_HATT;
    bf16_t* hEnt   = (bf16_t*)p; p += SZ_HENT;
    bf16_t* hEnt2  = (bf16_t*)p; p += SZ_HENT;
    bf16_t* Wih3   = (bf16_t*)p; p += SZ_WIH3;
    bf16_t* Whh3_a = (bf16_t*)p; p += SZ_WHH3E;
    bf16_t* Whh3_e = (bf16_t*)p; p += SZ_WHH3E;
    bf16_t* WfcB   = (bf16_t*)p; p += SZ_WFC;
    bf16_t* WgB    = (bf16_t*)p; p += SZ_WG;
    float*  asW    = (float*)p;  p += SZ_AW;
    float*  adW    = (float*)p;  p += SZ_AW;
    float*  es     = (float*)p;  p += SZ_VEC;
    float*  ed     = (float*)p;  p += SZ_VEC;
    bf16_t* nodes  = embB;       // overlay: embB+proj dead after GRU loops
    bf16_t* mixed  = hAtt[0];    // overlay: hAtt dead after fc_nodes_gemm

    // zero h ping-pong buffers (h0 = 0; pad cols must stay 0)
    hipMemsetAsync(hAtt[0], 0, SZ_HATT, stream);
    hipMemsetAsync(hAtt[1], 0, SZ_HATT, stream);
    hipMemsetAsync(hEnt,  0, SZ_HENT, stream);
    hipMemsetAsync(hEnt2, 0, SZ_HENT, stream);

    // prep (both GRUs use the INTERLEAVED n=3j+g layout)
    convert_emb_kernel<<<dim3((V_ * 40 + 255) / 256), 256, 0, stream>>>(emb, embB);
    build_w3i_kernel<<<dim3(HDIM * KPAD / 256), 256, 0, stream>>>(Wih_attr, Wih3);
    build_w3i_kernel<<<dim3(HDIM * KPAD / 256), 256, 0, stream>>>(Whh_attr, Whh3_a);
    build_w3i_kernel<<<dim3(HDIM * KPAD / 256), 256, 0, stream>>>(Whh_ent, Whh3_e);
    build_wfc_kernel<<<dim3(HDIM * KPAD / 256), 256, 0, stream>>>(Wfc, WfcB);
    build_wg_kernel<<<dim3(HDIM * HDIM / 256), 256, 0, stream>>>(Wg, WgB);
    asw_kernel<<<dim3(HDIM / 256), 256, 0, stream>>>(Wg, a_src, a_dst, asW, adW);

    // attr vocab projection (interleaved): proj[v] = embB[v] @ Wih3i_attr^T
    mfma_gemm<0><<<dim3(VP / 128, PROJW / 128), 256, 0, stream>>>(
        embB, Wih3, proj, KPAD, KPAD, PROJW, KPAD);

    // attr GRU: T=4 fused GEMM+epilogue steps, grid 256x8 = 2048 blocks
    for (int t = 0; t < TA_; ++t)
        gru_step_fused<<<dim3(GA / 128, 8), 512, 0, stream>>>(
            hAtt[t & 1], hAtt[(t + 1) & 1], Whh3_a, proj, at_tok, at_len,
            bih_attr, bhh_attr, TA_, t);

    // ent vocab projection (interleaved); overwrite proj
    build_w3i_kernel<<<dim3(HDIM * KPAD / 256), 256, 0, stream>>>(Wih_ent, Wih3);
    mfma_gemm<0><<<dim3(VP / 128, PROJW / 128), 256, 0, stream>>>(
        embB, Wih3, proj, KPAD, KPAD, PROJW, KPAD);

    // ent GRU: 8 fused GEMM+epilogue step launches, ping-pong h
    bf16_t* hb[2] = { hEnt, hEnt2 };
    for (int t = 0; t < TE_; ++t)
        gru_step_fused<<<dim3(G / 128, 8), 512, 0, stream>>>(
            hb[t & 1], hb[(t + 1) & 1], Whh3_e, proj, ent_tok, ent_len,
            bih_ent, bhh_ent, TE_, t);

    // nodes = relu(h @ Wfc^T + bfc) — proper GEMM with gathered A rows
    fc_nodes_gemm<<<dim3(MROWS / 128, HDIM / 128), 256, 0, stream>>>(
        hEnt, hAtt[0], WfcB, bfc, nodes);

    // es/ed = nodes . asW/adW (one wave per row)
    esed_kernel<<<dim3(MROWS / 4), 256, 0, stream>>>(nodes, asW, adW, es, ed);

    // row-0 softmax + node mixing
    attn_mix_kernel<<<dim3(G), 256, 0, stream>>>(nodes, es, ed, mixed);

    // out = elu(mixed @ Wg^T)
    mfma_gemm<2><<<dim3(G / 128, HDIM / 128), 256, 0, stream>>>(
        mixed, WgB, out, HDIM, HDIM, HDIM, HDIM);
}

// Round 9
// 729.444 us; speedup vs baseline: 1.4640x; 1.0467x over previous
//
#include <hip/hip_runtime.h>
#include <math.h>

namespace {

typedef unsigned short bf16_t;
typedef __bf16  bf16x8_t __attribute__((ext_vector_type(8)));
typedef float   f32x4_t  __attribute__((ext_vector_type(4)));
typedef unsigned int u32x4 __attribute__((ext_vector_type(4)));

constexpr int G     = 4096;      // BS*E
constexpr int GA    = 32768;     // G*A
constexpr int WDIM  = 300;
constexpr int KPAD  = 320;
constexpr int HDIM  = 1024;
constexpr int NNODE = 9;
constexpr int MROWS = G * NNODE; // 36864
constexpr int TE_   = 8;
constexpr int TA_   = 4;
constexpr int V_    = 30522;
constexpr int VP    = 30592;     // 239*128
constexpr int PROJW = 1024;

__device__ __forceinline__ float bf2f(bf16_t b) {
    union { unsigned int u; float f; } v; v.u = ((unsigned int)b) << 16; return v.f;
}
__device__ __forceinline__ bf16_t f2bf(float f) {
    union { float f; unsigned int u; } v; v.f = f;
    unsigned int r = v.u + 0x7FFFu + ((v.u >> 16) & 1u);   // RNE
    return (bf16_t)(r >> 16);
}

// R18 fast gates: v_exp + v_rcp (err ~1e-7, << bf16 quantum 4e-3).
// Saturation: exp->inf => rcp->0 (sig->1, tanh->1); exp->0 => sig->0, tanh->-1.
__device__ __forceinline__ float fast_sigmoid(float x) {
    return __builtin_amdgcn_rcpf(1.f + __expf(-x));
}
__device__ __forceinline__ float fast_tanh(float x) {
    return 1.f - 2.f * __builtin_amdgcn_rcpf(1.f + __expf(2.f * x));
}

// =====================================================================
// Generic 128x128-tile bf16 MFMA GEMM: C = A[M,K] @ B[N,K]^T
// MODE 0: C bf16 (vocab projection)   MODE 2: C fp32 with elu (final out)
// R16: LDS row stride 40. R18: register prefetch of next k-tile (the
// rolled loop stalled ~300cyc on vmcnt between the two barriers).
// =====================================================================
template<int MODE>
__global__ __launch_bounds__(256)
void mfma_gemm(const bf16_t* __restrict__ A, const bf16_t* __restrict__ B,
               void* __restrict__ Cv, int lda, int ldb, int ldc, int K)
{
    constexpr int AST = 40;                  // padded LDS row stride (bf16)
    __shared__ __align__(16) bf16_t As[128 * AST];   // 10 KB
    __shared__ __align__(16) bf16_t Bs[128 * AST];   // 10 KB

    const int tid  = threadIdx.x;
    const int w    = tid >> 6;
    const int lane = tid & 63;
    const int wr = w >> 1, wc = w & 1;
    const int lr = lane & 15;
    const int lk = lane >> 4;
    const int m0 = blockIdx.x * 128, n0 = blockIdx.y * 128;

    const int r0 = tid >> 2;
    const int cc = (tid & 3) * 8;
    const bf16_t* Arow0 = A + (size_t)(m0 + r0) * lda + cc;
    const bf16_t* Arow1 = Arow0 + (size_t)64 * lda;
    const bf16_t* Brow0 = B + (size_t)(n0 + r0) * ldb + cc;
    const bf16_t* Brow1 = Brow0 + (size_t)64 * ldb;

    f32x4_t acc[4][4];
#pragma unroll
    for (int i = 0; i < 4; ++i)
#pragma unroll
        for (int j = 0; j < 4; ++j) acc[i][j] = {0.f, 0.f, 0.f, 0.f};

    uint4 a0 = *(const uint4*)(Arow0);
    uint4 a1 = *(const uint4*)(Arow1);
    uint4 b0 = *(const uint4*)(Brow0);
    uint4 b1 = *(const uint4*)(Brow1);

    for (int k0 = 0; k0 < K; k0 += 32) {
        __syncthreads();
        *(uint4*)&As[r0 * AST + cc]        = a0;
        *(uint4*)&As[(r0 + 64) * AST + cc] = a1;
        *(uint4*)&Bs[r0 * AST + cc]        = b0;
        *(uint4*)&Bs[(r0 + 64) * AST + cc] = b1;
        if (k0 + 32 < K) {                   // prefetch next tile (hidden by MFMA)
            a0 = *(const uint4*)(Arow0 + k0 + 32);
            a1 = *(const uint4*)(Arow1 + k0 + 32);
            b0 = *(const uint4*)(Brow0 + k0 + 32);
            b1 = *(const uint4*)(Brow1 + k0 + 32);
        }
        __syncthreads();

        bf16x8_t af[4], bfr[4];
#pragma unroll
        for (int i = 0; i < 4; ++i) {
            af[i]  = *(const bf16x8_t*)&As[(wr * 64 + i * 16 + lr) * AST + lk * 8];
            bfr[i] = *(const bf16x8_t*)&Bs[(wc * 64 + i * 16 + lr) * AST + lk * 8];
        }
#pragma unroll
        for (int mi = 0; mi < 4; ++mi)
#pragma unroll
            for (int ni = 0; ni < 4; ++ni)
                acc[mi][ni] = __builtin_amdgcn_mfma_f32_16x16x32_bf16(
                    af[mi], bfr[ni], acc[mi][ni], 0, 0, 0);
    }

#pragma unroll
    for (int mi = 0; mi < 4; ++mi) {
#pragma unroll
        for (int ni = 0; ni < 4; ++ni) {
            const int n = n0 + wc * 64 + ni * 16 + lr;
#pragma unroll
            for (int r = 0; r < 4; ++r) {
                const int m = m0 + wr * 64 + mi * 16 + lk * 4 + r;
                const float v = acc[mi][ni][r];
                if (MODE == 0)
                    ((bf16_t*)Cv)[(size_t)m * ldc + n] = f2bf(v);
                else
                    ((float*)Cv)[(size_t)m * ldc + n] = v > 0.f ? v : expm1f(v);
            }
        }
    }
}

// =====================================================================
// GRU step (used for BOTH ent and attr). One launch per step; fused
// GEMM + gate epilogue. gates[M x 960] = h @ Whh3i^T, tile 128x120
// (interleaved n=3j+g), grid (M/128, 8), 512 thr. Scatter col<120 (R12).
// R18 post-mortem of R17: the As/Bs swizzle was a null lever (b128 reads
// were already at the LDS bandwidth floor; residual conflicts live in
// gsm) and epilogue prefetch was already compiler-hoisted. The real
// sinks per counters: VALU 35% (libm expf/tanhf in epilogue) and the
// per-iteration vmcnt stall on staging loads. R18: (a) fast_sigmoid /
// fast_tanh via v_exp+v_rcp; (b) register prefetch of the next k-tile
// issued between the barriers so MFMA hides the load latency.
// (Prefetch may over-read 16B past the last k-tile: lands in the next
// workspace buffer, value unused — bounds-checked safe.)
// =====================================================================
__global__ __launch_bounds__(512)
void gru_step_fused(const bf16_t* __restrict__ hin,     // [M][KPAD]
                    bf16_t* __restrict__ hout,          // [M][KPAD]
                    const bf16_t* __restrict__ Whh3i,   // [1024][320] n=3j+g
                    const bf16_t* __restrict__ proj,    // [VP][1024]  n=3j+g
                    const int* __restrict__ tokens,
                    const int* __restrict__ lengths,
                    const float* __restrict__ bih, const float* __restrict__ bhh,
                    int T, int t)
{
    constexpr int GSTRF = 123;               // odd f32 stride; 120 used cols
    __shared__ __align__(16) bf16_t As[128 * 32];   // 8 KB
    __shared__ __align__(16) bf16_t Bs[128 * 32];   // 8 KB
    __shared__ float gsm[128 * GSTRF];              // 61.5 KB

    const int tid = threadIdx.x;
    const int w = tid >> 6, lane = tid & 63;
    const int lr = lane & 15, lk = lane >> 4;
    const int wr = w >> 2, wc = w & 3;       // 2 (M) x 4 (N) waves
    const int m0 = blockIdx.x * 128;
    const int nb = blockIdx.y;               // 0..7
    const int n0 = nb * 120;

    // ---- epilogue operand prefetch (kept from R17, no harm) ----
    const int ml = tid >> 2, q = tid & 3;
    const int m  = m0 + ml;
    const int jb = nb * 40 + q * 10;
    const bool estore = !(nb == 7 && q >= 2);   // j >= 300 never stored
    int len = lengths[m]; if (len < 1) len = 1;
    const bool act = (t < len);
    const int tok = tokens[(size_t)m * T + t];

    const unsigned int* xpp =
        (const unsigned int*)(proj + (size_t)tok * PROJW + n0 + q * 30);
    unsigned int xw[15];
#pragma unroll
    for (int i = 0; i < 15; ++i) xw[i] = xpp[i];

    const unsigned int* hop = (const unsigned int*)(hin + (size_t)m * KPAD + jb);
    unsigned int hw[5];
#pragma unroll
    for (int i = 0; i < 5; ++i) hw[i] = hop[i];

    // ---- GEMM with register-prefetched staging ----
    const int sr = tid >> 2, sq = tid & 3;   // staging row / 16B-slot
    const bf16_t* Ap = hin   + (size_t)(m0 + sr) * KPAD + sq * 8;
    const bf16_t* Bp = Whh3i + (size_t)(n0 + sr) * KPAD + sq * 8;
    const int ssl = (sq ^ (sr & 3)) * 8;     // swizzled staging slot

    f32x4_t acc[4][2];
#pragma unroll
    for (int mi = 0; mi < 4; ++mi)
#pragma unroll
        for (int ni = 0; ni < 2; ++ni) acc[mi][ni] = {0.f, 0.f, 0.f, 0.f};

    uint4 av = *(const uint4*)(Ap);
    uint4 bv = *(const uint4*)(Bp);

    for (int k0 = 0; k0 < KPAD; k0 += 32) {
        __syncthreads();
        *(uint4*)&As[sr * 32 + ssl] = av;
        *(uint4*)&Bs[sr * 32 + ssl] = bv;
        if (k0 + 32 < KPAD) {                // prefetch next k-tile
            av = *(const uint4*)(Ap + k0 + 32);
            bv = *(const uint4*)(Bp + k0 + 32);
        }
        __syncthreads();

        // read slot swizzle: row&3 == lr&3 (row bases are multiples of 4)
        const int asl = (lk ^ (lr & 3)) * 8;
        bf16x8_t af[4], bfr[2];
#pragma unroll
        for (int mi = 0; mi < 4; ++mi)
            af[mi] = *(const bf16x8_t*)&As[(wr * 64 + mi * 16 + lr) * 32 + asl];
#pragma unroll
        for (int ni = 0; ni < 2; ++ni)
            bfr[ni] = *(const bf16x8_t*)&Bs[(wc * 32 + ni * 16 + lr) * 32 + asl];
#pragma unroll
        for (int mi = 0; mi < 4; ++mi)
#pragma unroll
            for (int ni = 0; ni < 2; ++ni)
                acc[mi][ni] = __builtin_amdgcn_mfma_f32_16x16x32_bf16(
                    af[mi], bfr[ni], acc[mi][ni], 0, 0, 0);
    }

    // scatter wave tiles to gates LDS (row = M, col = N); cols >= 120 are
    // the B-stage overlap belonging to the next nb block — DO NOT scatter
#pragma unroll
    for (int ni = 0; ni < 2; ++ni) {
        const int col = wc * 32 + ni * 16 + lr;
        if (col < 120) {
#pragma unroll
            for (int mi = 0; mi < 4; ++mi)
#pragma unroll
                for (int r = 0; r < 4; ++r)
                    gsm[(wr * 64 + mi * 16 + lk * 4 + r) * GSTRF + col]
                        = acc[mi][ni][r];
        }
    }
    __syncthreads();

    // ---- fused GRU epilogue (fast gates) ----
    unsigned int ow[5];
#pragma unroll
    for (int u = 0; u < 10; ++u) {
        const int j = jb + u;
        const bf16_t hob = (bf16_t)((u & 1) ? (hw[u >> 1] >> 16) : (hw[u >> 1] & 0xffff));
        const float hold = bf2f(hob);
        float hv = hold;
        if (act) {
            const int e0 = 3 * u;
            const float xr = bf2f((bf16_t)((e0 & 1)       ? (xw[e0 >> 1] >> 16)       : (xw[e0 >> 1] & 0xffff)));
            const float xz = bf2f((bf16_t)(((e0 + 1) & 1) ? (xw[(e0 + 1) >> 1] >> 16) : (xw[(e0 + 1) >> 1] & 0xffff)));
            const float xn = bf2f((bf16_t)(((e0 + 2) & 1) ? (xw[(e0 + 2) >> 1] >> 16) : (xw[(e0 + 2) >> 1] & 0xffff)));
            const int nl = q * 30 + 3 * u;
            const float g0 = gsm[ml * GSTRF + nl];
            const float g1 = gsm[ml * GSTRF + nl + 1];
            const float g2 = gsm[ml * GSTRF + nl + 2];
            const float rr = fast_sigmoid(g0 + xr + bih[j] + bhh[j]);
            const float zz = fast_sigmoid(g1 + xz + bih[WDIM + j] + bhh[WDIM + j]);
            const float nn = fast_tanh(xn + bih[2 * WDIM + j] + rr * (g2 + bhh[2 * WDIM + j]));
            hv = (1.f - zz) * nn + zz * hold;
        }
        const bf16_t hb_ = f2bf(hv);
        if ((u & 1) == 0) ow[u >> 1] = hb_;
        else              ow[u >> 1] |= ((unsigned int)hb_) << 16;
    }
    if (estore) {
        unsigned int* outp = (unsigned int*)(hout + (size_t)m * KPAD + jb);
#pragma unroll
        for (int i = 0; i < 5; ++i) outp[i] = ow[i];
    }
}

// =====================================================================
// R16: nodes = relu(h @ Wfc^T + bfc) as a PROPER 128x128 GEMM with a
// gathered A (128-entry LDS pointer table). Stride-40 LDS.
// R18: register prefetch of next k-tile.
// =====================================================================
__global__ __launch_bounds__(256)
void fc_nodes_gemm(const bf16_t* __restrict__ hEnt, const bf16_t* __restrict__ hAtt,
                   const bf16_t* __restrict__ WfcB, const float* __restrict__ bfc,
                   bf16_t* __restrict__ nodes)
{
    constexpr int AST = 40;
    __shared__ __align__(16) bf16_t As[128 * AST];   // 10 KB
    __shared__ __align__(16) bf16_t Bs[128 * AST];   // 10 KB
    __shared__ const bf16_t* rowp[128];

    const int tid  = threadIdx.x;
    const int w    = tid >> 6;
    const int lane = tid & 63;
    const int wr = w >> 1, wc = w & 1;
    const int lr = lane & 15;
    const int lk = lane >> 4;
    const int m0 = blockIdx.x * 128, n0 = blockIdx.y * 128;

    if (tid < 128) {
        const int m = m0 + tid;
        const int g = m / NNODE, i = m - g * NNODE;
        rowp[tid] = (i == 0) ? (hEnt + (size_t)g * KPAD)
                             : (hAtt + (size_t)(g * 8 + (i - 1)) * KPAD);
    }
    __syncthreads();

    const int r0 = tid >> 2;
    const int cc = (tid & 3) * 8;
    const bf16_t* Arow0 = rowp[r0] + cc;
    const bf16_t* Arow1 = rowp[r0 + 64] + cc;
    const bf16_t* Brow0 = WfcB + (size_t)(n0 + r0) * KPAD + cc;
    const bf16_t* Brow1 = Brow0 + (size_t)64 * KPAD;

    f32x4_t acc[4][4];
#pragma unroll
    for (int i = 0; i < 4; ++i)
#pragma unroll
        for (int j = 0; j < 4; ++j) acc[i][j] = {0.f, 0.f, 0.f, 0.f};

    uint4 a0 = *(const uint4*)(Arow0);
    uint4 a1 = *(const uint4*)(Arow1);
    uint4 b0 = *(const uint4*)(Brow0);
    uint4 b1 = *(const uint4*)(Brow1);

    for (int k0 = 0; k0 < KPAD; k0 += 32) {
        __syncthreads();
        *(uint4*)&As[r0 * AST + cc]        = a0;
        *(uint4*)&As[(r0 + 64) * AST + cc] = a1;
        *(uint4*)&Bs[r0 * AST + cc]        = b0;
        *(uint4*)&Bs[(r0 + 64) * AST + cc] = b1;
        if (k0 + 32 < KPAD) {
            a0 = *(const uint4*)(Arow0 + k0 + 32);
            a1 = *(const uint4*)(Arow1 + k0 + 32);
            b0 = *(const uint4*)(Brow0 + k0 + 32);
            b1 = *(const uint4*)(Brow1 + k0 + 32);
        }
        __syncthreads();

        bf16x8_t af[4], bfr[4];
#pragma unroll
        for (int i = 0; i < 4; ++i) {
            af[i]  = *(const bf16x8_t*)&As[(wr * 64 + i * 16 + lr) * AST + lk * 8];
            bfr[i] = *(const bf16x8_t*)&Bs[(wc * 64 + i * 16 + lr) * AST + lk * 8];
        }
#pragma unroll
        for (int mi = 0; mi < 4; ++mi)
#pragma unroll
            for (int ni = 0; ni < 4; ++ni)
                acc[mi][ni] = __builtin_amdgcn_mfma_f32_16x16x32_bf16(
                    af[mi], bfr[ni], acc[mi][ni], 0, 0, 0);
    }

#pragma unroll
    for (int mi = 0; mi < 4; ++mi) {
#pragma unroll
        for (int ni = 0; ni < 4; ++ni) {
            const int n = n0 + wc * 64 + ni * 16 + lr;
            const float bb = bfc[n];
#pragma unroll
            for (int r = 0; r < 4; ++r) {
                const int m = m0 + wr * 64 + mi * 16 + lk * 4 + r;
                float v = acc[mi][ni][r] + bb;
                v = v > 0.f ? v : 0.f;
                nodes[(size_t)m * HDIM + n] = f2bf(v);
            }
        }
    }
}

// es[m] = nodes[m] . asW ; ed[m] = nodes[m] . adW. One wave per row.
__global__ __launch_bounds__(256)
void esed_kernel(const bf16_t* __restrict__ nodes,
                 const float* __restrict__ asW, const float* __restrict__ adW,
                 float* __restrict__ es, float* __restrict__ ed)
{
    const int m    = (blockIdx.x * 256 + threadIdx.x) >> 6;   // row
    const int lane = threadIdx.x & 63;
    const bf16_t* row = nodes + (size_t)m * HDIM;

    const uint4 v0 = *(const uint4*)(row + lane * 8);
    const uint4 v1 = *(const uint4*)(row + 512 + lane * 8);

    float s = 0.f, d = 0.f;
    const unsigned int* w0 = (const unsigned int*)&v0;
    const unsigned int* w1 = (const unsigned int*)&v1;
#pragma unroll
    for (int e = 0; e < 4; ++e) {
        const int c0 = lane * 8 + 2 * e;
        const float x0 = bf2f((bf16_t)(w0[e] & 0xffff));
        const float x1 = bf2f((bf16_t)(w0[e] >> 16));
        s = fmaf(x0, asW[c0], s);     s = fmaf(x1, asW[c0 + 1], s);
        d = fmaf(x0, adW[c0], d);     d = fmaf(x1, adW[c0 + 1], d);
        const int c1 = 512 + lane * 8 + 2 * e;
        const float y0 = bf2f((bf16_t)(w1[e] & 0xffff));
        const float y1 = bf2f((bf16_t)(w1[e] >> 16));
        s = fmaf(y0, asW[c1], s);     s = fmaf(y1, asW[c1 + 1], s);
        d = fmaf(y0, adW[c1], d);     d = fmaf(y1, adW[c1 + 1], d);
    }
#pragma unroll
    for (int mask = 1; mask < 64; mask <<= 1) {
        s += __shfl_xor(s, mask, 64);
        d += __shfl_xor(d, mask, 64);
    }
    if (lane == 0) { es[m] = s; ed[m] = d; }
}

// =====================================================================
// Prep kernels
// =====================================================================
__global__ __launch_bounds__(256)
void convert_emb_kernel(const float* __restrict__ emb, bf16_t* __restrict__ embB)
{
    const int idx = blockIdx.x * 256 + threadIdx.x;    // over V_*40
    if (idx >= V_ * 40) return;
    const int row = idx / 40, c8 = (idx - row * 40) * 8;
    bf16_t o[8];
#pragma unroll
    for (int e = 0; e < 8; ++e) {
        const int c = c8 + e;
        o[e] = (c < WDIM) ? f2bf(emb[(size_t)row * WDIM + c]) : (bf16_t)0;
    }
    *(ushort4*)(embB + (size_t)row * KPAD + c8)     = *(ushort4*)&o[0];
    *(ushort4*)(embB + (size_t)row * KPAD + c8 + 4) = *(ushort4*)&o[4];
}

// W [3*300][300] fp32 -> dst[1024][320] bf16, INTERLEAVED rows n = 3*j + g
__global__ __launch_bounds__(256)
void build_w3i_kernel(const float* __restrict__ W, bf16_t* __restrict__ dst)
{
    const int idx = blockIdx.x * 256 + threadIdx.x;    // over 1024*320
    if (idx >= HDIM * KPAD) return;
    const int n = idx / KPAD, k = idx - n * KPAD;
    float v = 0.f;
    if (n < 960) {
        const int j = n / 3, g = n - j * 3;
        if (j < WDIM && k < WDIM)
            v = W[(size_t)(g * WDIM + j) * WDIM + k];
    }
    dst[idx] = f2bf(v);
}

__global__ __launch_bounds__(256)
void build_wfc_kernel(const float* __restrict__ Wfc, bf16_t* __restrict__ Wb)
{
    const int idx = blockIdx.x * 256 + threadIdx.x;    // over 1024*320
    if (idx >= HDIM * KPAD) return;
    const int n = idx / KPAD, k = idx - n * KPAD;
    Wb[idx] = f2bf(k < WDIM ? Wfc[(size_t)n * WDIM + k] : 0.f);
}

__global__ __launch_bounds__(256)
void build_wg_kernel(const float* __restrict__ Wg, bf16_t* __restrict__ Wb)
{
    const int idx = blockIdx.x * 256 + threadIdx.x;    // over 1024*1024
    Wb[idx] = f2bf(Wg[idx]);
}

// asW = a_src @ Wg, adW = a_dst @ Wg
__global__ __launch_bounds__(256)
void asw_kernel(const float* __restrict__ Wg,
                const float* __restrict__ a_src, const float* __restrict__ a_dst,
                float* __restrict__ asW, float* __restrict__ adW)
{
    const int k = blockIdx.x * 256 + threadIdx.x;
    float s = 0.f, d = 0.f;
    for (int n = 0; n < HDIM; ++n) {
        const float w = Wg[(size_t)n * HDIM + k];
        s = fmaf(a_src[n], w, s);
        d = fmaf(a_dst[n], w, d);
    }
    asW[k] = s; adW[k] = d;
}

// Row-0 star attention -> mixed[g] = sum_j alpha_j * nodes[g*9+j] (bf16)
__global__ __launch_bounds__(256)
void attn_mix_kernel(const bf16_t* __restrict__ nodes,
                     const float* __restrict__ es, const float* __restrict__ ed,
                     bf16_t* __restrict__ mixed)
{
    const int g = blockIdx.x;
    const float e0 = es[(size_t)g * NNODE];
    const float* edg = ed + (size_t)g * NNODE;

    float w[NNODE], mx = -1e30f;
#pragma unroll
    for (int j = 0; j < NNODE; ++j) {
        float v = e0 + edg[j];
        v = v >= 0.f ? v : 0.2f * v;
        w[j] = v; mx = fmaxf(mx, v);
    }
    float denom = 0.f;
#pragma unroll
    for (int j = 0; j < NNODE; ++j) { w[j] = expf(w[j] - mx); denom += w[j]; }
    const float inv = 1.f / denom;

    const int c = threadIdx.x * 4;
    float4 acc = {0.f, 0.f, 0.f, 0.f};
#pragma unroll
    for (int j = 0; j < NNODE; ++j) {
        const float a = w[j] * inv;
        const ushort4 h4 = *(const ushort4*)(nodes + (size_t)(g * NNODE + j) * HDIM + c);
        acc.x = fmaf(a, bf2f(h4.x), acc.x);
        acc.y = fmaf(a, bf2f(h4.y), acc.y);
        acc.z = fmaf(a, bf2f(h4.z), acc.z);
        acc.w = fmaf(a, bf2f(h4.w), acc.w);
    }
    ushort4 o;
    o.x = f2bf(acc.x); o.y = f2bf(acc.y); o.z = f2bf(acc.z); o.w = f2bf(acc.w);
    *(ushort4*)(mixed + (size_t)g * HDIM + c) = o;
}

// -------- workspace layout (~134 MiB; 157 MiB known-safe) --------
constexpr size_t SZ_EMBB  = (size_t)VP * KPAD * sizeof(bf16_t);      // 19.58 MB
constexpr size_t SZ_PROJ  = (size_t)VP * PROJW * sizeof(bf16_t);     // 62.65 MB
constexpr size_t SZ_HATT  = (size_t)GA * KPAD * sizeof(bf16_t);      // 20.97 MB x2
constexpr size_t SZ_HENT  = (size_t)G * KPAD * sizeof(bf16_t);       //  2.62 MB x2
constexpr size_t SZ_WIH3  = (size_t)HDIM * KPAD * sizeof(bf16_t);
constexpr size_t SZ_WHH3E = (size_t)HDIM * KPAD * sizeof(bf16_t);    //  0.66 MB x2 (1024 rows)
constexpr size_t SZ_WFC   = (size_t)HDIM * KPAD * sizeof(bf16_t);
constexpr size_t SZ_WG    = (size_t)HDIM * HDIM * sizeof(bf16_t);
constexpr size_t SZ_AW    = (size_t)HDIM * sizeof(float);
constexpr size_t SZ_VEC   = (size_t)MROWS * sizeof(float);
constexpr size_t SZ_NODE  = (size_t)MROWS * HDIM * sizeof(bf16_t);   // 75.5 MB
constexpr size_t SZ_MIX   = (size_t)G * HDIM * sizeof(bf16_t);
constexpr size_t WS_NEED  = SZ_EMBB + SZ_PROJ + 2 * SZ_HATT + 2 * SZ_HENT +
                            SZ_WIH3 + 2 * SZ_WHH3E + SZ_WFC + SZ_WG +
                            2 * SZ_AW + 2 * SZ_VEC;
static_assert(SZ_NODE <= SZ_EMBB + SZ_PROJ, "nodes overlays embB+proj");
static_assert(SZ_MIX  <= 2 * SZ_HATT,       "mixed overlays hAtt pair");

} // namespace

extern "C" void kernel_launch(void* const* d_in, const int* in_sizes, int n_in,
                              void* d_out, int out_size, void* d_ws, size_t ws_size,
                              hipStream_t stream)
{
    (void)in_sizes; (void)n_in; (void)out_size;
    if (ws_size < WS_NEED) return;   // clean absmax failure instead of fault

    const int*   ent_tok  = (const int*)  d_in[0];
    const int*   ent_len  = (const int*)  d_in[1];
    const int*   at_tok   = (const int*)  d_in[3];
    const int*   at_len   = (const int*)  d_in[4];
    const float* emb      = (const float*)d_in[6];
    const float* Wih_ent  = (const float*)d_in[7];
    const float* Whh_ent  = (const float*)d_in[8];
    const float* bih_ent  = (const float*)d_in[9];
    const float* bhh_ent  = (const float*)d_in[10];
    const float* Wih_attr = (const float*)d_in[11];
    const float* Whh_attr = (const float*)d_in[12];
    const float* bih_attr = (const float*)d_in[13];
    const float* bhh_attr = (const float*)d_in[14];
    const float* Wfc      = (const float*)d_in[15];
    const float* bfc      = (const float*)d_in[16];
    const float* Wg       = (const float*)d_in[17];
    const float* a_src    = (const float*)d_in[18];
    const float* a_dst    = (const float*)d_in[19];
    float* out = (float*)d_out;

    char* p = (char*)d_ws;
    bf16_t* embB  = (bf16_t*)p; p += SZ_EMBB;
    bf16_t* proj  = (bf16_t*)p; p += SZ_PROJ;
    bf16_t* hAtt[2];
    hAtt[0] = (bf16_t*)p; p += SZ_HATT;
    hAtt[1] = (bf16_t*)p; p += SZ_HATT;
    bf16_t* hEnt   = (bf16_t*)p; p += SZ_HENT;
    bf16_t* hEnt2  = (bf16_t*)p; p += SZ_HENT;
    bf16_t* Wih3   = (bf16_t*)p; p += SZ_WIH3;
    bf16_t* Whh3_a = (bf16_t*)p; p += SZ_WHH3E;
    bf16_t* Whh3_e = (bf16_t*)p; p += SZ_WHH3E;
    bf16_t* WfcB   = (bf16_t*)p; p += SZ_WFC;
    bf16_t* WgB    = (bf16_t*)p; p += SZ_WG;
    float*  asW    = (float*)p;  p += SZ_AW;
    float*  adW    = (float*)p;  p += SZ_AW;
    float*  es     = (float*)p;  p += SZ_VEC;
    float*  ed     = (float*)p;  p += SZ_VEC;
    bf16_t* nodes  = embB;       // overlay: embB+proj dead after GRU loops
    bf16_t* mixed  = hAtt[0];    // overlay: hAtt dead after fc_nodes_gemm

    // zero h ping-pong buffers (h0 = 0; pad cols must stay 0)
    hipMemsetAsync(hAtt[0], 0, SZ_HATT, stream);
    hipMemsetAsync(hAtt[1], 0, SZ_HATT, stream);
    hipMemsetAsync(hEnt,  0, SZ_HENT, stream);
    hipMemsetAsync(hEnt2, 0, SZ_HENT, stream);

    // prep (both GRUs use the INTERLEAVED n=3j+g layout)
    convert_emb_kernel<<<dim3((V_ * 40 + 255) / 256), 256, 0, stream>>>(emb, embB);
    build_w3i_kernel<<<dim3(HDIM * KPAD / 256), 256, 0, stream>>>(Wih_attr, Wih3);
    build_w3i_kernel<<<dim3(HDIM * KPAD / 256), 256, 0, stream>>>(Whh_attr, Whh3_a);
    build_w3i_kernel<<<dim3(HDIM * KPAD / 256), 256, 0, stream>>>(Whh_ent, Whh3_e);
    build_wfc_kernel<<<dim3(HDIM * KPAD / 256), 256, 0, stream>>>(Wfc, WfcB);
    build_wg_kernel<<<dim3(HDIM * HDIM / 256), 256, 0, stream>>>(Wg, WgB);
    asw_kernel<<<dim3(HDIM / 256), 256, 0, stream>>>(Wg, a_src, a_dst, asW, adW);

    // attr vocab projection (interleaved): proj[v] = embB[v] @ Wih3i_attr^T
    mfma_gemm<0><<<dim3(VP / 128, PROJW / 128), 256, 0, stream>>>(
        embB, Wih3, proj, KPAD, KPAD, PROJW, KPAD);

    // attr GRU: T=4 fused GEMM+epilogue steps, grid 256x8 = 2048 blocks
    for (int t = 0; t < TA_; ++t)
        gru_step_fused<<<dim3(GA / 128, 8), 512, 0, stream>>>(
            hAtt[t & 1], hAtt[(t + 1) & 1], Whh3_a, proj, at_tok, at_len,
            bih_attr, bhh_attr, TA_, t);

    // ent vocab projection (interleaved); overwrite proj
    build_w3i_kernel<<<dim3(HDIM * KPAD / 256), 256, 0, stream>>>(Wih_ent, Wih3);
    mfma_gemm<0><<<dim3(VP / 128, PROJW / 128), 256, 0, stream>>>(
        embB, Wih3, proj, KPAD, KPAD, PROJW, KPAD);

    // ent GRU: 8 fused GEMM+epilogue step launches, ping-pong h
    bf16_t* hb[2] = { hEnt, hEnt2 };
    for (int t = 0; t < TE_; ++t)
        gru_step_fused<<<dim3(G / 128, 8), 512, 0, stream>>>(
            hb[t & 1], hb[(t + 1) & 1], Whh3_e, proj, ent_tok, ent_len,
            bih_ent, bhh_ent, TE_, t);

    // nodes = relu(h @ Wfc^T + bfc) — proper GEMM with gathered A rows
    fc_nodes_gemm<<<dim3(MROWS / 128, HDIM / 128), 256, 0, stream>>>(
        hEnt, hAtt[0], WfcB, bfc, nodes);

    // es/ed = nodes . asW/adW (one wave per row)
    esed_kernel<<<dim3(MROWS / 4), 256, 0, stream>>>(nodes, asW, adW, es, ed);

    // row-0 softmax + node mixing
    attn_mix_kernel<<<dim3(G), 256, 0, stream>>>(nodes, es, ed, mixed);

    // out = elu(mixed @ Wg^T)
    mfma_gemm<2><<<dim3(G / 128, HDIM / 128), 256, 0, stream>>>(
        mixed, WgB, out, HDIM, HDIM, HDIM, HDIM);
}